// Round 7
// baseline (5775.972 us; speedup 1.0000x reference)
//
#include <hip/hip_runtime.h>
#include <math.h>

#define T_STEPS 512
#define BATCH   512

__device__ __forceinline__ float sigmoidf_(float x) {
    return 1.0f / (1.0f + __expf(-x));        // x<<0 -> 1/inf = 0, safe
}
__device__ __forceinline__ float tanhf_(float x) {
    float ax = fabsf(x);
    float e  = __expf(-2.0f * ax);            // in (0,1], never overflows
    float t  = (1.0f - e) / (1.0f + e);
    return copysignf(t, x);
}
__device__ __forceinline__ float4 ld4(const float* p) {
    return make_float4(p[0], p[1], p[2], p[3]);
}

#define PINF(f)  asm volatile("" : "+v"(f))
#define PIN4(v)  { PINF(v.x); PINF(v.y); PINF(v.z); PINF(v.w); }

// ---------------------------------------------------------------------------
// gemm1: xg[r][j] = b[j] + sum_k A[r][k]*W[j][k], K=64, N=400. (unchanged)
// ---------------------------------------------------------------------------
__global__ __launch_bounds__(448, 2) void gemm1_kernel(
    const float* __restrict__ A, const float* __restrict__ W,
    const float* __restrict__ bih, const float* __restrict__ bhh,
    float* __restrict__ xg)
{
    __shared__ __align__(16) float As[64 * 64];
    const int tid = threadIdx.x;

    float4 W00,W01,W02,W03,W04,W05,W06,W07,W08,W09,W10,W11,W12,W13,W14,W15;
    float bias = 0.0f;
    if (tid < 400) {
        bias = bih[tid] + bhh[tid];
        const float* wp = W + tid * 64;
        W00=ld4(wp+ 0); W01=ld4(wp+ 4); W02=ld4(wp+ 8); W03=ld4(wp+12);
        W04=ld4(wp+16); W05=ld4(wp+20); W06=ld4(wp+24); W07=ld4(wp+28);
        W08=ld4(wp+32); W09=ld4(wp+36); W10=ld4(wp+40); W11=ld4(wp+44);
        W12=ld4(wp+48); W13=ld4(wp+52); W14=ld4(wp+56); W15=ld4(wp+60);
    }

    const size_t r0 = (size_t)blockIdx.x * 64;
    const float4* Ag = (const float4*)(A + r0 * 64);
    float4* As4 = (float4*)As;
    for (int i = tid; i < 64 * 16; i += 448) As4[i] = Ag[i];
    __syncthreads();

    if (tid < 400) {
        for (int r = 0; r < 64; ++r) {
            const float4* a4 = (const float4*)(As + r * 64);
            float a0 = bias, a1 = 0.0f;
#define G1V(WV, I) { float4 v = a4[I]; \
            a0 = fmaf(v.x, WV.x, a0); a1 = fmaf(v.y, WV.y, a1); \
            a0 = fmaf(v.z, WV.z, a0); a1 = fmaf(v.w, WV.w, a1); }
            G1V(W00,0) G1V(W01,1) G1V(W02,2) G1V(W03,3)
            G1V(W04,4) G1V(W05,5) G1V(W06,6) G1V(W07,7)
            G1V(W08,8) G1V(W09,9) G1V(W10,10) G1V(W11,11)
            G1V(W12,12) G1V(W13,13) G1V(W14,14) G1V(W15,15)
#undef G1V
            xg[(r0 + r) * 400 + tid] = a0 + a1;
        }
    }
}

// ---------------------------------------------------------------------------
// gemm2: K=100, N=200, split-K slots. (unchanged)
// ---------------------------------------------------------------------------
__global__ __launch_bounds__(448, 2) void gemm2_kernel(
    const float* __restrict__ A, const float* __restrict__ W,
    const float* __restrict__ bih, const float* __restrict__ bhh,
    float* __restrict__ xg)
{
    __shared__ __align__(16) float As[64 * 104];
    __shared__ __align__(16) float ps[8][2][200];

    const int tid  = threadIdx.x;
    const bool slot = (tid < 400);
    const int q = slot ? tid / 200 : 0;
    const int j = slot ? tid % 200 : 0;

    float4 W00,W01,W02,W03,W04,W05,W06,W07,W08,W09,W10,W11,W12;
    float bias = 0.0f;
    if (slot) {
        if (q == 0) bias = bih[j] + bhh[j];
        const float* wp = W + j * 100 + q * 52;
        W00=ld4(wp+ 0); W01=ld4(wp+ 4); W02=ld4(wp+ 8); W03=ld4(wp+12);
        W04=ld4(wp+16); W05=ld4(wp+20); W06=ld4(wp+24); W07=ld4(wp+28);
        W08=ld4(wp+32); W09=ld4(wp+36); W10=ld4(wp+40); W11=ld4(wp+44);
        W12 = q ? make_float4(0.f,0.f,0.f,0.f) : ld4(wp+48);
    }

    const size_t r0 = (size_t)blockIdx.x * 64;
    const float2* A2 = (const float2*)(A + r0 * 100);
    float2* As2 = (float2*)As;
    for (int i = tid; i < 64 * 50; i += 448) {
        int r = i / 50, k2 = i % 50;
        As2[r * 52 + k2] = A2[i];
    }
    if (tid < 64) {
        As[tid*104+100]=0.f; As[tid*104+101]=0.f;
        As[tid*104+102]=0.f; As[tid*104+103]=0.f;
    }
    __syncthreads();

    const float4* As4 = (const float4*)As;
    const int q13 = q * 13;
    const float base = (q == 0) ? bias : 0.0f;
    for (int g = 0; g < 8; ++g) {
        const int rb = g * 8;
        if (slot) {
#define G2V(P, WV, I) { float4 v = P[I]; \
            A0 = fmaf(v.x, WV.x, A0); A1 = fmaf(v.y, WV.y, A1); \
            A0 = fmaf(v.z, WV.z, A0); A1 = fmaf(v.w, WV.w, A1); }
#define G2ROW(RR) { const float4* a4 = As4 + (rb + RR) * 26 + q13; \
            float A0 = base, A1 = 0.0f; \
            G2V(a4,W00,0) G2V(a4,W01,1) G2V(a4,W02,2) G2V(a4,W03,3) \
            G2V(a4,W04,4) G2V(a4,W05,5) G2V(a4,W06,6) G2V(a4,W07,7) \
            G2V(a4,W08,8) G2V(a4,W09,9) G2V(a4,W10,10) G2V(a4,W11,11) \
            G2V(a4,W12,12) \
            ps[RR][q][j] = A0 + A1; }
            G2ROW(0) G2ROW(1) G2ROW(2) G2ROW(3)
            G2ROW(4) G2ROW(5) G2ROW(6) G2ROW(7)
#undef G2ROW
#undef G2V
        }
        __syncthreads();
        if (tid < 200) {
            #pragma unroll
            for (int rr = 0; rr < 8; ++rr)
                xg[(r0 + rb + rr) * 200 + tid] = ps[rr][0][tid] + ps[rr][1][tid];
        }
        __syncthreads();
    }
}

// ---------------------------------------------------------------------------
// scan1 (REDESIGNED): gate-ownership. 512 blocks (1 batch row, 2 blocks/CU),
// 256 threads. Thread t<200: unit u=t%100, K-half q=t/100; owns ALL 4 gates
// of unit u over k in [52q, 52q+52) -> 208 weight floats. One h-broadcast
// read feeds 4 gates (LDS instr/step cut ~5x vs round 6). q=0 thread also
// does the pointwise update (i,f,g,o local after tiny ps exchange).
// ---------------------------------------------------------------------------
__global__ __launch_bounds__(256, 2) void scan1_kernel(
    const float* __restrict__ xg,     // [CH*B, 400] chunk-local
    const float* __restrict__ w_hh,   // [400, 100]
    float* __restrict__ h1c,          // [CH*B, 100] chunk-local
    float* __restrict__ c1state,      // [B, 100]
    int t0, int CH)
{
    __shared__ __align__(16) float h_s[2][104];   // double-buffered h, pad=0
    __shared__ __align__(16) float ps[2][4][100]; // [q][gate][unit]

    const int tid = threadIdx.x;
    const int row = blockIdx.x;
    const bool act = (tid < 200);
    const int u = act ? tid % 100 : 0;
    const int q = act ? tid / 100 : 0;

    float4 A0,A1,A2,A3,A4,A5,A6,A7,A8,A9,A10,A11,A12;      // gate i
    float4 B0,B1,B2,B3,B4,B5,B6,B7,B8,B9,B10,B11,B12;      // gate f
    float4 C0,C1,C2,C3,C4,C5,C6,C7,C8,C9,C10,C11,C12;      // gate g
    float4 D0,D1,D2,D3,D4,D5,D6,D7,D8,D9,D10,D11,D12;      // gate o
#define S1LD(P, base) \
    P##0=ld4(base+0);  P##1=ld4(base+4);  P##2=ld4(base+8);  P##3=ld4(base+12); \
    P##4=ld4(base+16); P##5=ld4(base+20); P##6=ld4(base+24); P##7=ld4(base+28); \
    P##8=ld4(base+32); P##9=ld4(base+36); P##10=ld4(base+40); P##11=ld4(base+44); \
    P##12 = q ? make_float4(0.f,0.f,0.f,0.f) : ld4(base+48); \
    PIN4(P##0) PIN4(P##1) PIN4(P##2) PIN4(P##3) PIN4(P##4) PIN4(P##5) \
    PIN4(P##6) PIN4(P##7) PIN4(P##8) PIN4(P##9) PIN4(P##10) PIN4(P##11) PIN4(P##12)
    if (act) {
        const float* wi = w_hh + (0 * 100 + u) * 100 + q * 52;
        const float* wf = w_hh + (1 * 100 + u) * 100 + q * 52;
        const float* wg = w_hh + (2 * 100 + u) * 100 + q * 52;
        const float* wo = w_hh + (3 * 100 + u) * 100 + q * 52;
        S1LD(A, wi) S1LD(B, wf) S1LD(C, wg) S1LD(D, wo)
    }
#undef S1LD

    // init h_s (both buffers + pads), c, first xg
    if (tid < 208) { int b = tid / 104, i = tid % 104; h_s[b][i] = 0.0f; }
    float c = 0.0f;
    __syncthreads();
    if (t0 > 0 && tid < 100) {
        h_s[0][u] = h1c[((size_t)(CH - 1) * BATCH + row) * 100 + u];
        c         = c1state[(size_t)row * 100 + u];
    }
    float xgI = 0.f, xgF = 0.f, xgG = 0.f, xgO = 0.f;
    if (tid < 100) {
        const float* xp = xg + (size_t)row * 400 + u;
        xgI = xp[0]; xgF = xp[100]; xgG = xp[200]; xgO = xp[300];
    }
    __syncthreads();

    for (int tl = 0; tl < CH; ++tl) {
        // ---- phase A: gate dot-products + next-step xg prefetch ----
        float pI = 0.f, pF = 0.f, pG = 0.f, pO = 0.f;
        if (tid < 100 && tl + 1 < CH) {
            const float* xp = xg + ((size_t)(tl + 1) * BATCH + row) * 400 + u;
            pI = xp[0]; pF = xp[100]; pG = xp[200]; pO = xp[300];
        }
        if (act) {
            const float4* hv = (const float4*)h_s[tl & 1] + q * 13;
            float aI = q ? 0.f : xgI, aF = q ? 0.f : xgF;
            float aG = q ? 0.f : xgG, aO = q ? 0.f : xgO;
#define S1F(I) { float4 v = hv[I]; \
            aI=fmaf(v.x,A##I.x,aI); aF=fmaf(v.x,B##I.x,aF); aG=fmaf(v.x,C##I.x,aG); aO=fmaf(v.x,D##I.x,aO); \
            aI=fmaf(v.y,A##I.y,aI); aF=fmaf(v.y,B##I.y,aF); aG=fmaf(v.y,C##I.y,aG); aO=fmaf(v.y,D##I.y,aO); \
            aI=fmaf(v.z,A##I.z,aI); aF=fmaf(v.z,B##I.z,aF); aG=fmaf(v.z,C##I.z,aG); aO=fmaf(v.z,D##I.z,aO); \
            aI=fmaf(v.w,A##I.w,aI); aF=fmaf(v.w,B##I.w,aF); aG=fmaf(v.w,C##I.w,aG); aO=fmaf(v.w,D##I.w,aO); }
            S1F(0) S1F(1) S1F(2) S1F(3) S1F(4) S1F(5) S1F(6)
            S1F(7) S1F(8) S1F(9) S1F(10) S1F(11) S1F(12)
#undef S1F
            ps[q][0][u] = aI; ps[q][1][u] = aF;
            ps[q][2][u] = aG; ps[q][3][u] = aO;
        }
        __syncthreads();
        xgI = pI; xgF = pF; xgG = pG; xgO = pO;
        // ---- phase B: pointwise update (q=0 thread of each unit) ----
        if (tid < 100) {
            float gi = ps[0][0][u] + ps[1][0][u];
            float gf = ps[0][1][u] + ps[1][1][u];
            float gg = ps[0][2][u] + ps[1][2][u];
            float go = ps[0][3][u] + ps[1][3][u];
            c = sigmoidf_(gf) * c + sigmoidf_(gi) * tanhf_(gg);
            float h = sigmoidf_(go) * tanhf_(c);
            h_s[(tl + 1) & 1][u] = h;
            h1c[((size_t)tl * BATCH + row) * 100 + u] = h;
        }
        __syncthreads();
    }
    if (tid < 100) c1state[(size_t)row * 100 + u] = c;
}

// ---------------------------------------------------------------------------
// scan23 (REDESIGNED): 512 blocks (1 row), 128 threads, pipelined L2/L3/lin.
//   t 0..49   : L2 unit u, all 4 gates (4x13 vec4 of w_hh2), local update.
//   t 64..113 : L3 unit u3=(t-64)%25, pair p=(t-64)/25: gates (2p,2p+1),
//               each gate = 13 vec4 (w_ih3, 50-wide) + 7 vec4 (w_hh3, 25-wide).
//               p=1 sends its 2 dots via ps3; p=0 owns c3/h3 update.
//   t == 120  : final linear (7 vec4).
// iteration it: L2 step it, L3 step it-1, linear step it-2.
// ---------------------------------------------------------------------------
__global__ __launch_bounds__(128, 2) void scan23_kernel(
    const float* __restrict__ xg2,    // [CH*B, 200] (biases folded)
    const float* __restrict__ w_hh2,  // [200, 50]
    const float* __restrict__ w_ih3,  // [100, 50]
    const float* __restrict__ w_hh3,  // [100, 25]
    const float* __restrict__ b_ih3, const float* __restrict__ b_hh3,
    const float* __restrict__ w_lin, const float* __restrict__ b_lin,
    float* __restrict__ out,          // [T*B]
    float* __restrict__ h2state, float* __restrict__ c2state,  // [B,50]
    float* __restrict__ h3state, float* __restrict__ c3state,  // [B,25]
    int t0, int CH)
{
    __shared__ __align__(16) float h2_s[2][52];
    __shared__ __align__(16) float x3_s[2][52];
    __shared__ __align__(16) float h3_s[2][28];
    __shared__ __align__(16) float h3o_s[2][28];
    __shared__ __align__(16) float ps3[2][25];

    const int tid = threadIdx.x;
    const int row = blockIdx.x;

    const bool isL2 = (tid < 50);
    const bool isL3 = (tid >= 64 && tid < 114);
    const bool isLin = (tid == 120);
    const int u2 = isL2 ? tid : 0;
    const int u3 = isL3 ? (tid - 64) % 25 : 0;
    const int p3 = isL3 ? (tid - 64) / 25 : 0;

    // L2 weights: 4 gates x 13 vec4 (50-wide rows, vec12 = (w48,w49,0,0))
    float4 A0,A1,A2,A3,A4,A5,A6,A7,A8,A9,A10,A11,A12;
    float4 B0,B1,B2,B3,B4,B5,B6,B7,B8,B9,B10,B11,B12;
    float4 C0,C1,C2,C3,C4,C5,C6,C7,C8,C9,C10,C11,C12;
    float4 D0,D1,D2,D3,D4,D5,D6,D7,D8,D9,D10,D11,D12;
    // L3 pair weights: gate a = WA(13, ih) + WB(7, hh); gate b = WC + WD.
    // Linear reuses WB0..WB6.
    float4 WA0,WA1,WA2,WA3,WA4,WA5,WA6,WA7,WA8,WA9,WA10,WA11,WA12;
    float4 WB0,WB1,WB2,WB3,WB4,WB5,WB6;
    float4 WC0,WC1,WC2,WC3,WC4,WC5,WC6,WC7,WC8,WC9,WC10,WC11,WC12;
    float4 WD0,WD1,WD2,WD3,WD4,WD5,WD6;
    float biasA = 0.f, biasB = 0.f;

#define LD50(P, base) \
    P##0=ld4(base+0);  P##1=ld4(base+4);  P##2=ld4(base+8);  P##3=ld4(base+12); \
    P##4=ld4(base+16); P##5=ld4(base+20); P##6=ld4(base+24); P##7=ld4(base+28); \
    P##8=ld4(base+32); P##9=ld4(base+36); P##10=ld4(base+40); P##11=ld4(base+44); \
    P##12 = make_float4(base[48], base[49], 0.f, 0.f);
#define LD25(P, base) \
    P##0=ld4(base+0);  P##1=ld4(base+4);  P##2=ld4(base+8); \
    P##3=ld4(base+12); P##4=ld4(base+16); P##5=ld4(base+20); \
    P##6 = make_float4(base[24], 0.f, 0.f, 0.f);

    if (isL2) {
        LD50(A, (w_hh2 + (0 * 50 + u2) * 50))
        LD50(B, (w_hh2 + (1 * 50 + u2) * 50))
        LD50(C, (w_hh2 + (2 * 50 + u2) * 50))
        LD50(D, (w_hh2 + (3 * 50 + u2) * 50))
    } else if (isL3) {
        const int ja = (2 * p3)     * 25 + u3;
        const int jb = (2 * p3 + 1) * 25 + u3;
        biasA = b_ih3[ja] + b_hh3[ja];
        biasB = b_ih3[jb] + b_hh3[jb];
        LD50(WA, (w_ih3 + ja * 50))
        LD25(WB, (w_hh3 + ja * 25))
        LD50(WC, (w_ih3 + jb * 50))
        LD25(WD, (w_hh3 + jb * 25))
    } else if (isLin) {
        biasA = b_lin[0];
        LD25(WB, w_lin)
    }
#undef LD50
#undef LD25

    // init LDS state + pads
    if (tid < 104) { int b = tid / 52, i = tid % 52; h2_s[b][i] = 0.f; x3_s[b][i] = 0.f; }
    if (tid >= 104 && tid < 128) { int k = tid - 104; int b = k / 12, i = k % 12;
        if (i < 28) { /*always*/ } h3_s[b][i] = 0.f; h3o_s[b][i] = 0.f; }
    // threads 104..127 cover [2][12] only; finish pads explicitly:
    if (tid < 2) { for (int i = 12; i < 28; ++i) { h3_s[tid][i] = 0.f; h3o_s[tid][i] = 0.f; } }
    float c2 = 0.f, c3 = 0.f;
    __syncthreads();
    if (t0 > 0) {
        if (isL2) {
            h2_s[0][u2] = h2state[(size_t)row * 50 + u2];
            c2          = c2state[(size_t)row * 50 + u2];
        }
        if (isL3 && p3 == 0) {
            h3_s[0][u3] = h3state[(size_t)row * 25 + u3];
            c3          = c3state[(size_t)row * 25 + u3];
        }
    }
    float xI = 0.f, xF = 0.f, xG = 0.f, xO = 0.f;
    if (isL2) {
        const float* xp = xg2 + (size_t)row * 200 + u2;
        xI = xp[0]; xF = xp[50]; xG = xp[100]; xO = xp[150];
    }
    __syncthreads();

    for (int it = 0; it < CH + 2; ++it) {
        // ---------------- phase A ----------------
        float pI = 0.f, pF = 0.f, pG = 0.f, pO = 0.f;
        if (isL2 && it + 1 < CH) {
            const float* xp = xg2 + ((size_t)(it + 1) * BATCH + row) * 200 + u2;
            pI = xp[0]; pF = xp[50]; pG = xp[100]; pO = xp[150];
        }
        float aI = 0.f, aF = 0.f, aG = 0.f, aO = 0.f;   // L2 gates
        float aA = biasA, aB = biasB;                   // L3 pair gates
        if (isL2 && it < CH) {
            const float4* hv = (const float4*)h2_s[it & 1];
            aI = xI; aF = xF; aG = xG; aO = xO;
#define L2F(I) { float4 v = hv[I]; \
            aI=fmaf(v.x,A##I.x,aI); aF=fmaf(v.x,B##I.x,aF); aG=fmaf(v.x,C##I.x,aG); aO=fmaf(v.x,D##I.x,aO); \
            aI=fmaf(v.y,A##I.y,aI); aF=fmaf(v.y,B##I.y,aF); aG=fmaf(v.y,C##I.y,aG); aO=fmaf(v.y,D##I.y,aO); \
            aI=fmaf(v.z,A##I.z,aI); aF=fmaf(v.z,B##I.z,aF); aG=fmaf(v.z,C##I.z,aG); aO=fmaf(v.z,D##I.z,aO); \
            aI=fmaf(v.w,A##I.w,aI); aF=fmaf(v.w,B##I.w,aF); aG=fmaf(v.w,C##I.w,aG); aO=fmaf(v.w,D##I.w,aO); }
            L2F(0) L2F(1) L2F(2) L2F(3) L2F(4) L2F(5) L2F(6)
            L2F(7) L2F(8) L2F(9) L2F(10) L2F(11) L2F(12)
#undef L2F
        }
        if (isL3 && it >= 1 && it <= CH) {
            const int s3 = it - 1;
            const float4* xv = (const float4*)x3_s[s3 & 1];
            const float4* hv = (const float4*)h3_s[s3 & 1];
#define L3X(I) { float4 v = xv[I]; \
            aA=fmaf(v.x,WA##I.x,aA); aB=fmaf(v.x,WC##I.x,aB); \
            aA=fmaf(v.y,WA##I.y,aA); aB=fmaf(v.y,WC##I.y,aB); \
            aA=fmaf(v.z,WA##I.z,aA); aB=fmaf(v.z,WC##I.z,aB); \
            aA=fmaf(v.w,WA##I.w,aA); aB=fmaf(v.w,WC##I.w,aB); }
#define L3H(I) { float4 v = hv[I]; \
            aA=fmaf(v.x,WB##I.x,aA); aB=fmaf(v.x,WD##I.x,aB); \
            aA=fmaf(v.y,WB##I.y,aA); aB=fmaf(v.y,WD##I.y,aB); \
            aA=fmaf(v.z,WB##I.z,aA); aB=fmaf(v.z,WD##I.z,aB); \
            aA=fmaf(v.w,WB##I.w,aA); aB=fmaf(v.w,WD##I.w,aB); }
            L3X(0) L3X(1) L3X(2) L3X(3) L3X(4) L3X(5) L3X(6)
            L3X(7) L3X(8) L3X(9) L3X(10) L3X(11) L3X(12)
            L3H(0) L3H(1) L3H(2) L3H(3) L3H(4) L3H(5) L3H(6)
#undef L3X
#undef L3H
            if (p3 == 1) { ps3[0][u3] = aA; ps3[1][u3] = aB; }
        }
        if (isLin && it >= 2) {
            const float4* hv = (const float4*)h3o_s[(it - 2) & 1];
            float o0 = biasA, o1 = 0.f;
#define LNF(I) { float4 v = hv[I]; \
            o0 = fmaf(v.x, WB##I.x, o0); o1 = fmaf(v.y, WB##I.y, o1); \
            o0 = fmaf(v.z, WB##I.z, o0); o1 = fmaf(v.w, WB##I.w, o1); }
            LNF(0) LNF(1) LNF(2) LNF(3) LNF(4) LNF(5) LNF(6)
#undef LNF
            out[(size_t)(t0 + it - 2) * BATCH + row] = o0 + o1;
        }
        __syncthreads();

        // ---------------- phase B ----------------
        if (isL2) { xI = pI; xF = pF; xG = pG; xO = pO; }
        if (isL2 && it < CH) {
            c2 = sigmoidf_(aF) * c2 + sigmoidf_(aI) * tanhf_(aG);
            float h = sigmoidf_(aO) * tanhf_(c2);
            h2_s[(it + 1) & 1][u2] = h;
            x3_s[it & 1][u2] = h;
        }
        if (isL3 && p3 == 0 && it >= 1 && it <= CH) {
            const int s3 = it - 1;
            float gg = ps3[0][u3], go = ps3[1][u3];
            c3 = sigmoidf_(aB) * c3 + sigmoidf_(aA) * tanhf_(gg);
            float h = sigmoidf_(go) * tanhf_(c3);
            h3_s[(s3 + 1) & 1][u3] = h;
            h3o_s[s3 & 1][u3] = h;
        }
        __syncthreads();
    }

    if (isL2) {
        h2state[(size_t)row * 50 + u2] = h2_s[CH & 1][u2];
        c2state[(size_t)row * 50 + u2] = c2;
    }
    if (isL3 && p3 == 0) {
        h3state[(size_t)row * 25 + u3] = h3_s[CH & 1][u3];
        c3state[(size_t)row * 25 + u3] = c3;
    }
}

extern "C" void kernel_launch(void* const* d_in, const int* in_sizes, int n_in,
                              void* d_out, int out_size, void* d_ws, size_t ws_size,
                              hipStream_t stream)
{
    const float* x     = (const float*)d_in[0];
    const float* w_ih1 = (const float*)d_in[1];
    const float* w_hh1 = (const float*)d_in[2];
    const float* b_ih1 = (const float*)d_in[3];
    const float* b_hh1 = (const float*)d_in[4];
    const float* w_ih2 = (const float*)d_in[5];
    const float* w_hh2 = (const float*)d_in[6];
    const float* b_ih2 = (const float*)d_in[7];
    const float* b_hh2 = (const float*)d_in[8];
    const float* w_ih3 = (const float*)d_in[9];
    const float* w_hh3 = (const float*)d_in[10];
    const float* b_ih3 = (const float*)d_in[11];
    const float* b_hh3 = (const float*)d_in[12];
    const float* w_lin = (const float*)d_in[13];
    const float* b_lin = (const float*)d_in[14];
    float* out = (float*)d_out;

    const size_t state_bytes = (size_t)BATCH * (100 + 50 + 50 + 25 + 25) * sizeof(float);
    int CH = 0;
    for (int c = 128; c >= 8; c >>= 1) {
        size_t need = (size_t)c * BATCH * 700 * sizeof(float) + state_bytes;
        if (need <= ws_size) { CH = c; break; }
    }
    if (CH == 0) return;  // soft-fail: workspace too small

    char* ws = (char*)d_ws;
    float* xg1c    = (float*)ws;                                   // CH*B*400
    float* h1c     = xg1c + (size_t)CH * BATCH * 400;              // CH*B*100
    float* xg2c    = h1c  + (size_t)CH * BATCH * 100;              // CH*B*200
    float* c1state = xg2c + (size_t)CH * BATCH * 200;              // B*100
    float* h2state = c1state + (size_t)BATCH * 100;                // B*50
    float* c2state = h2state + (size_t)BATCH * 50;                 // B*50
    float* h3state = c2state + (size_t)BATCH * 50;                 // B*25
    float* c3state = h3state + (size_t)BATCH * 25;                 // B*25

    const int rowtiles = CH * BATCH / 64;

    for (int t0 = 0; t0 < T_STEPS; t0 += CH) {
        gemm1_kernel<<<rowtiles, 448, 0, stream>>>(
            x + (size_t)t0 * BATCH * 64, w_ih1, b_ih1, b_hh1, xg1c);
        scan1_kernel<<<BATCH, 256, 0, stream>>>(xg1c, w_hh1, h1c, c1state, t0, CH);
        gemm2_kernel<<<rowtiles, 448, 0, stream>>>(h1c, w_ih2, b_ih2, b_hh2, xg2c);
        scan23_kernel<<<BATCH, 128, 0, stream>>>(
            xg2c, w_hh2, w_ih3, w_hh3, b_ih3, b_hh3, w_lin, b_lin, out,
            h2state, c2state, h3state, c3state, t0, CH);
    }
}

// Round 8
// 2623.976 us; speedup vs baseline: 2.2012x; 2.2012x over previous
//
#include <hip/hip_runtime.h>
#include <math.h>

#define T_STEPS 512
#define BATCH   512

__device__ __forceinline__ float sigmoidf_(float x) {
    return 1.0f / (1.0f + __expf(-x));        // x<<0 -> 1/inf = 0, safe
}
__device__ __forceinline__ float tanhf_(float x) {
    float ax = fabsf(x);
    float e  = __expf(-2.0f * ax);            // in (0,1], never overflows
    float t  = (1.0f - e) / (1.0f + e);
    return copysignf(t, x);
}
__device__ __forceinline__ float4 ld4(const float* p) {
    return make_float4(p[0], p[1], p[2], p[3]);
}

#define PINF(f)  asm volatile("" : "+v"(f))
#define PIN4(v)  { PINF(v.x); PINF(v.y); PINF(v.z); PINF(v.w); }

// ---------------------------------------------------------------------------
// gemm1: xg[r][j] = b[j] + sum_k A[r][k]*W[j][k], K=64, N=400. (round-6)
// ---------------------------------------------------------------------------
__global__ __launch_bounds__(448, 2) void gemm1_kernel(
    const float* __restrict__ A, const float* __restrict__ W,
    const float* __restrict__ bih, const float* __restrict__ bhh,
    float* __restrict__ xg)
{
    __shared__ __align__(16) float As[64 * 64];
    const int tid = threadIdx.x;

    float4 W00,W01,W02,W03,W04,W05,W06,W07,W08,W09,W10,W11,W12,W13,W14,W15;
    float bias = 0.0f;
    if (tid < 400) {
        bias = bih[tid] + bhh[tid];
        const float* wp = W + tid * 64;
        W00=ld4(wp+ 0); W01=ld4(wp+ 4); W02=ld4(wp+ 8); W03=ld4(wp+12);
        W04=ld4(wp+16); W05=ld4(wp+20); W06=ld4(wp+24); W07=ld4(wp+28);
        W08=ld4(wp+32); W09=ld4(wp+36); W10=ld4(wp+40); W11=ld4(wp+44);
        W12=ld4(wp+48); W13=ld4(wp+52); W14=ld4(wp+56); W15=ld4(wp+60);
    }

    const size_t r0 = (size_t)blockIdx.x * 64;
    const float4* Ag = (const float4*)(A + r0 * 64);
    float4* As4 = (float4*)As;
    for (int i = tid; i < 64 * 16; i += 448) As4[i] = Ag[i];
    __syncthreads();

    if (tid < 400) {
        for (int r = 0; r < 64; ++r) {
            const float4* a4 = (const float4*)(As + r * 64);
            float a0 = bias, a1 = 0.0f;
#define G1V(WV, I) { float4 v = a4[I]; \
            a0 = fmaf(v.x, WV.x, a0); a1 = fmaf(v.y, WV.y, a1); \
            a0 = fmaf(v.z, WV.z, a0); a1 = fmaf(v.w, WV.w, a1); }
            G1V(W00,0) G1V(W01,1) G1V(W02,2) G1V(W03,3)
            G1V(W04,4) G1V(W05,5) G1V(W06,6) G1V(W07,7)
            G1V(W08,8) G1V(W09,9) G1V(W10,10) G1V(W11,11)
            G1V(W12,12) G1V(W13,13) G1V(W14,14) G1V(W15,15)
#undef G1V
            xg[(r0 + r) * 400 + tid] = a0 + a1;
        }
    }
}

// ---------------------------------------------------------------------------
// gemm2: K=100, N=200, split-K slots. (round-6)
// ---------------------------------------------------------------------------
__global__ __launch_bounds__(448, 2) void gemm2_kernel(
    const float* __restrict__ A, const float* __restrict__ W,
    const float* __restrict__ bih, const float* __restrict__ bhh,
    float* __restrict__ xg)
{
    __shared__ __align__(16) float As[64 * 104];
    __shared__ __align__(16) float ps[8][2][200];

    const int tid  = threadIdx.x;
    const bool slot = (tid < 400);
    const int q = slot ? tid / 200 : 0;
    const int j = slot ? tid % 200 : 0;

    float4 W00,W01,W02,W03,W04,W05,W06,W07,W08,W09,W10,W11,W12;
    float bias = 0.0f;
    if (slot) {
        if (q == 0) bias = bih[j] + bhh[j];
        const float* wp = W + j * 100 + q * 52;
        W00=ld4(wp+ 0); W01=ld4(wp+ 4); W02=ld4(wp+ 8); W03=ld4(wp+12);
        W04=ld4(wp+16); W05=ld4(wp+20); W06=ld4(wp+24); W07=ld4(wp+28);
        W08=ld4(wp+32); W09=ld4(wp+36); W10=ld4(wp+40); W11=ld4(wp+44);
        W12 = q ? make_float4(0.f,0.f,0.f,0.f) : ld4(wp+48);
    }

    const size_t r0 = (size_t)blockIdx.x * 64;
    const float2* A2 = (const float2*)(A + r0 * 100);
    float2* As2 = (float2*)As;
    for (int i = tid; i < 64 * 50; i += 448) {
        int r = i / 50, k2 = i % 50;
        As2[r * 52 + k2] = A2[i];
    }
    if (tid < 64) {
        As[tid*104+100]=0.f; As[tid*104+101]=0.f;
        As[tid*104+102]=0.f; As[tid*104+103]=0.f;
    }
    __syncthreads();

    const float4* As4 = (const float4*)As;
    const int q13 = q * 13;
    const float base = (q == 0) ? bias : 0.0f;
    for (int g = 0; g < 8; ++g) {
        const int rb = g * 8;
        if (slot) {
#define G2V(P, WV, I) { float4 v = P[I]; \
            A0 = fmaf(v.x, WV.x, A0); A1 = fmaf(v.y, WV.y, A1); \
            A0 = fmaf(v.z, WV.z, A0); A1 = fmaf(v.w, WV.w, A1); }
#define G2ROW(RR) { const float4* a4 = As4 + (rb + RR) * 26 + q13; \
            float A0 = base, A1 = 0.0f; \
            G2V(a4,W00,0) G2V(a4,W01,1) G2V(a4,W02,2) G2V(a4,W03,3) \
            G2V(a4,W04,4) G2V(a4,W05,5) G2V(a4,W06,6) G2V(a4,W07,7) \
            G2V(a4,W08,8) G2V(a4,W09,9) G2V(a4,W10,10) G2V(a4,W11,11) \
            G2V(a4,W12,12) \
            ps[RR][q][j] = A0 + A1; }
            G2ROW(0) G2ROW(1) G2ROW(2) G2ROW(3)
            G2ROW(4) G2ROW(5) G2ROW(6) G2ROW(7)
#undef G2ROW
#undef G2V
        }
        __syncthreads();
        if (tid < 200) {
            #pragma unroll
            for (int rr = 0; rr < 8; ++rr)
                xg[(r0 + rb + rr) * 200 + tid] = ps[rr][0][tid] + ps[rr][1][tid];
        }
        __syncthreads();
    }
}

// ---------------------------------------------------------------------------
// scan1 (LDS-WEIGHTS REDESIGN): W_hh1 fp32 lives in LDS (160000 B), staged
// once per launch. 256 blocks (2 batch rows), 256 threads (4 waves).
// Thread t<200: unit u=t>>1, row r=t&1 -> owns all 4 gates of unit u for
// its row: per step 100 b128 w-reads (lane pairs broadcast, banks even) +
// 25 b128 h-reads (own row) + 400 FMA. No per-thread weight state -> no
// spill possible (~45 VGPR). No partial exchange; single h buffer.
// Dynamic LDS: 160000 (wt) + 400 (hA) + 400 (hB) = 160800 B.
// ---------------------------------------------------------------------------
__global__ __launch_bounds__(256, 1) void scan1_kernel(
    const float* __restrict__ xg,     // [CH*B, 400] chunk-local
    const float* __restrict__ w_hh,   // [400, 100]
    float* __restrict__ h1c,          // [CH*B, 100] chunk-local
    float* __restrict__ c1state,      // [B, 100]
    int t0, int CH)
{
    extern __shared__ __align__(16) char smem[];
    float4* wt = (float4*)smem;                    // [25][400]: wt[m*400+j] = W[j][4m..4m+3]
    float* hA = (float*)(smem + 160000);           // h row 0 [100]
    float* hB = (float*)(smem + 160400);           // h row 1 [100]

    const int tid = threadIdx.x;
    const int brow0 = blockIdx.x * 2;

    // stage W: global row-major [400][100] -> LDS k-quad-major [25][400]
    for (int e = tid; e < 10000; e += 256) {
        int j = e % 400, m = e / 400;
        wt[m * 400 + j] = *(const float4*)(w_hh + j * 100 + 4 * m);
    }

    const bool act = (tid < 200);
    const int u = tid >> 1;
    const int r = tid & 1;
    const int row = brow0 + r;

    float c = 0.0f;
    if (act) {
        float h0 = 0.0f;
        if (t0 > 0) {
            h0 = h1c[((size_t)(CH - 1) * BATCH + row) * 100 + u];
            c  = c1state[(size_t)row * 100 + u];
        }
        (r ? hB : hA)[u] = h0;
    }
    float xI = 0.f, xF = 0.f, xG = 0.f, xO = 0.f;
    if (act) {
        const float* xp = xg + (size_t)row * 400 + u;
        xI = xp[0]; xF = xp[100]; xG = xp[200]; xO = xp[300];
    }
    __syncthreads();

    const float4* hr = (const float4*)(r ? hB : hA);
    float* hw = r ? hB : hA;

    for (int tl = 0; tl < CH; ++tl) {
        // prefetch next step's xg into regs (hides global latency under FMAs)
        float pI = 0.f, pF = 0.f, pG = 0.f, pO = 0.f;
        if (act && tl + 1 < CH) {
            const float* xp = xg + ((size_t)(tl + 1) * BATCH + row) * 400 + u;
            pI = xp[0]; pF = xp[100]; pG = xp[200]; pO = xp[300];
        }
        float aI = xI, aF = xF, aG = xG, aO = xO;
        if (act) {
            const float4* wp = wt + u;
            #pragma unroll
            for (int m = 0; m < 25; ++m) {
                float4 hv = hr[m];
                float4 wi = wp[0], wf = wp[100], wg = wp[200], wo = wp[300];
                wp += 400;
                aI = fmaf(hv.x, wi.x, aI); aF = fmaf(hv.x, wf.x, aF);
                aG = fmaf(hv.x, wg.x, aG); aO = fmaf(hv.x, wo.x, aO);
                aI = fmaf(hv.y, wi.y, aI); aF = fmaf(hv.y, wf.y, aF);
                aG = fmaf(hv.y, wg.y, aG); aO = fmaf(hv.y, wo.y, aO);
                aI = fmaf(hv.z, wi.z, aI); aF = fmaf(hv.z, wf.z, aF);
                aG = fmaf(hv.z, wg.z, aG); aO = fmaf(hv.z, wo.z, aO);
                aI = fmaf(hv.w, wi.w, aI); aF = fmaf(hv.w, wf.w, aF);
                aG = fmaf(hv.w, wg.w, aG); aO = fmaf(hv.w, wo.w, aO);
            }
        }
        __syncthreads();   // all h reads of this step done
        if (act) {
            c = sigmoidf_(aF) * c + sigmoidf_(aI) * tanhf_(aG);
            float h = sigmoidf_(aO) * tanhf_(c);
            hw[u] = h;
            h1c[((size_t)tl * BATCH + row) * 100 + u] = h;
            xI = pI; xF = pF; xG = pG; xO = pO;
        }
        __syncthreads();   // h writes visible for next step
    }
    if (act) c1state[(size_t)row * 100 + u] = c;
}

// ---------------------------------------------------------------------------
// scan23: layers 2+3 + linear, pipelined (round-6 version, measured OK).
// ---------------------------------------------------------------------------
__global__ __launch_bounds__(384, 2) void scan23_kernel(
    const float* __restrict__ xg2,    // [CH*B, 200] chunk-local (biases folded)
    const float* __restrict__ w_hh2,  // [200, 50]
    const float* __restrict__ w_ih3,  // [100, 50]
    const float* __restrict__ w_hh3,  // [100, 25]
    const float* __restrict__ b_ih3, const float* __restrict__ b_hh3,
    const float* __restrict__ w_lin, const float* __restrict__ b_lin,
    float* __restrict__ out,          // [T*B]
    float* __restrict__ h2state, float* __restrict__ c2state,  // [B,50]
    float* __restrict__ h3state, float* __restrict__ c3state,  // [B,25]
    int t0, int CH)
{
    __shared__ __align__(16) float h2_s[52];
    __shared__ __align__(16) float x3_s[2][52];
    __shared__ __align__(16) float h3_s[28];
    __shared__ __align__(16) float h3o_s[2][28];
    __shared__ __align__(16) float g2_s[200];
    __shared__ __align__(16) float g3_s[100];

    const int tid  = threadIdx.x;
    const int brow = blockIdx.x;

    float4 WA0,WA1,WA2,WA3,WA4,WA5,WA6,WA7,WA8,WA9,WA10,WA11,WA12;
    float4 WB0,WB1,WB2,WB3,WB4,WB5,WB6;
    float bias = 0.0f;

#define PINA13 { PIN4(WA0) PIN4(WA1) PIN4(WA2) PIN4(WA3) PIN4(WA4) PIN4(WA5) \
                 PIN4(WA6) PIN4(WA7) PIN4(WA8) PIN4(WA9) PIN4(WA10) PIN4(WA11) \
                 PIN4(WA12) }
#define PINB7  { PIN4(WB0) PIN4(WB1) PIN4(WB2) PIN4(WB3) PIN4(WB4) PIN4(WB5) \
                 PIN4(WB6) }

    if (tid < 200) {                       // L2 gates: w_hh2 row (50 + 2 zeros)
        const float* p = w_hh2 + tid * 50;
        WA0=ld4(p+ 0); WA1=ld4(p+ 4); WA2=ld4(p+ 8); WA3=ld4(p+12);
        WA4=ld4(p+16); WA5=ld4(p+20); WA6=ld4(p+24); WA7=ld4(p+28);
        WA8=ld4(p+32); WA9=ld4(p+36); WA10=ld4(p+40); WA11=ld4(p+44);
        WA12 = make_float4(p[48], p[49], 0.f, 0.f);
        PINA13
    } else if (tid >= 256 && tid < 356) {  // L3 gates
        int jj = tid - 256;
        bias = b_ih3[jj] + b_hh3[jj];
        const float* p = w_ih3 + jj * 50;
        WA0=ld4(p+ 0); WA1=ld4(p+ 4); WA2=ld4(p+ 8); WA3=ld4(p+12);
        WA4=ld4(p+16); WA5=ld4(p+20); WA6=ld4(p+24); WA7=ld4(p+28);
        WA8=ld4(p+32); WA9=ld4(p+36); WA10=ld4(p+40); WA11=ld4(p+44);
        WA12 = make_float4(p[48], p[49], 0.f, 0.f);
        const float* p2 = w_hh3 + jj * 25;
        WB0=ld4(p2+ 0); WB1=ld4(p2+ 4); WB2=ld4(p2+ 8);
        WB3=ld4(p2+12); WB4=ld4(p2+16); WB5=ld4(p2+20);
        WB6 = make_float4(p2[24], 0.f, 0.f, 0.f);
        PINA13
        PINB7
        PINF(bias);
    } else if (tid == 370) {               // linear (7 vecs in WA0..WA6)
        bias = b_lin[0];
        WA0=ld4(w_lin+ 0); WA1=ld4(w_lin+ 4); WA2=ld4(w_lin+ 8);
        WA3=ld4(w_lin+12); WA4=ld4(w_lin+16); WA5=ld4(w_lin+20);
        WA6 = make_float4(w_lin[24], 0.f, 0.f, 0.f);
        PIN4(WA0) PIN4(WA1) PIN4(WA2) PIN4(WA3) PIN4(WA4) PIN4(WA5) PIN4(WA6)
        PINF(bias);
    }
#undef PINA13
#undef PINB7

    float c2 = 0.0f, c3 = 0.0f;
    if (tid < 52)  { h2_s[tid] = 0.0f; x3_s[0][tid] = 0.0f; x3_s[1][tid] = 0.0f; }
    if (tid >= 52 && tid < 80)  h3_s[tid - 52] = 0.0f;
    if (tid >= 80 && tid < 108) h3o_s[0][tid - 80] = 0.0f;
    if (tid >= 108 && tid < 136) h3o_s[1][tid - 108] = 0.0f;
    __syncthreads();
    if (t0 > 0) {
        if (tid < 50) {
            h2_s[tid] = h2state[(size_t)brow * 50 + tid];
            c2        = c2state[(size_t)brow * 50 + tid];
        }
        if (tid >= 256 && tid < 281) {
            int u = tid - 256;
            h3_s[u] = h3state[(size_t)brow * 25 + u];
            c3      = c3state[(size_t)brow * 25 + u];
        }
    }
    float xgv = (tid < 200) ? xg2[(size_t)brow * 200 + tid] : 0.0f;
    __syncthreads();

    for (int it = 0; it < CH + 2; ++it) {
        float pre = (tid < 200 && it + 1 < CH)
                  ? xg2[((size_t)(it + 1) * BATCH + brow) * 200 + tid] : 0.0f;

        if (tid < 200 && it < CH) {                 // L2 gates, step t0+it
            const float4* hv = (const float4*)h2_s;
            float a0 = xgv, a1 = 0.0f;
#define SCV(PV, WV, I) { float4 v = PV[I]; \
            a0 = fmaf(v.x, WV.x, a0); a1 = fmaf(v.y, WV.y, a1); \
            a0 = fmaf(v.z, WV.z, a0); a1 = fmaf(v.w, WV.w, a1); }
            SCV(hv,WA0,0) SCV(hv,WA1,1) SCV(hv,WA2,2) SCV(hv,WA3,3)
            SCV(hv,WA4,4) SCV(hv,WA5,5) SCV(hv,WA6,6) SCV(hv,WA7,7)
            SCV(hv,WA8,8) SCV(hv,WA9,9) SCV(hv,WA10,10) SCV(hv,WA11,11)
            SCV(hv,WA12,12)
            g2_s[tid] = a0 + a1;
        }

        if (tid >= 256 && tid < 356 && it >= 1 && it <= CH) {  // L3 gates
            const float4* xv = (const float4*)x3_s[(it - 1) & 1];
            const float4* hv = (const float4*)h3_s;
            float a0 = bias, a1 = 0.0f;
            SCV(xv,WA0,0) SCV(xv,WA1,1) SCV(xv,WA2,2) SCV(xv,WA3,3)
            SCV(xv,WA4,4) SCV(xv,WA5,5) SCV(xv,WA6,6) SCV(xv,WA7,7)
            SCV(xv,WA8,8) SCV(xv,WA9,9) SCV(xv,WA10,10) SCV(xv,WA11,11)
            SCV(xv,WA12,12)
            SCV(hv,WB0,0) SCV(hv,WB1,1) SCV(hv,WB2,2) SCV(hv,WB3,3)
            SCV(hv,WB4,4) SCV(hv,WB5,5) SCV(hv,WB6,6)
            g3_s[tid - 256] = a0 + a1;
        }

        if (tid == 370 && it >= 2) {               // linear
            const float4* hv = (const float4*)h3o_s[(it - 2) & 1];
            float a0 = bias, a1 = 0.0f;
            SCV(hv,WA0,0) SCV(hv,WA1,1) SCV(hv,WA2,2) SCV(hv,WA3,3)
            SCV(hv,WA4,4) SCV(hv,WA5,5) SCV(hv,WA6,6)
            out[(size_t)(t0 + it - 2) * BATCH + brow] = a0 + a1;
        }
#undef SCV
        __syncthreads();

        if (tid < 200) xgv = pre;

        if (tid < 50 && it < CH) {                  // L2 update
            float gi = g2_s[tid],       gf = g2_s[50 + tid];
            float gg = g2_s[100 + tid], go = g2_s[150 + tid];
            c2 = sigmoidf_(gf) * c2 + sigmoidf_(gi) * tanhf_(gg);
            float h = sigmoidf_(go) * tanhf_(c2);
            h2_s[tid] = h;
            x3_s[it & 1][tid] = h;
        }

        if (tid >= 256 && tid < 281 && it >= 1 && it <= CH) {  // L3 update
            int u = tid - 256;
            float gi = g3_s[u],      gf = g3_s[25 + u];
            float gg = g3_s[50 + u], go = g3_s[75 + u];
            c3 = sigmoidf_(gf) * c3 + sigmoidf_(gi) * tanhf_(gg);
            float h = sigmoidf_(go) * tanhf_(c3);
            h3_s[u] = h;
            h3o_s[(it - 1) & 1][u] = h;
        }
        __syncthreads();
    }

    if (tid < 50) {
        h2state[(size_t)brow * 50 + tid] = h2_s[tid];
        c2state[(size_t)brow * 50 + tid] = c2;
    }
    if (tid >= 256 && tid < 281) {
        int u = tid - 256;
        h3state[(size_t)brow * 25 + u] = h3_s[u];
        c3state[(size_t)brow * 25 + u] = c3;
    }
}

extern "C" void kernel_launch(void* const* d_in, const int* in_sizes, int n_in,
                              void* d_out, int out_size, void* d_ws, size_t ws_size,
                              hipStream_t stream)
{
    const float* x     = (const float*)d_in[0];
    const float* w_ih1 = (const float*)d_in[1];
    const float* w_hh1 = (const float*)d_in[2];
    const float* b_ih1 = (const float*)d_in[3];
    const float* b_hh1 = (const float*)d_in[4];
    const float* w_ih2 = (const float*)d_in[5];
    const float* w_hh2 = (const float*)d_in[6];
    const float* b_ih2 = (const float*)d_in[7];
    const float* b_hh2 = (const float*)d_in[8];
    const float* w_ih3 = (const float*)d_in[9];
    const float* w_hh3 = (const float*)d_in[10];
    const float* b_ih3 = (const float*)d_in[11];
    const float* b_hh3 = (const float*)d_in[12];
    const float* w_lin = (const float*)d_in[13];
    const float* b_lin = (const float*)d_in[14];
    float* out = (float*)d_out;

    // scan1 uses 160800 B dynamic LDS (gfx950 allows up to 160 KiB/WG).
    const int SCAN1_LDS = 160000 + 400 + 400;
    (void)hipFuncSetAttribute((const void*)scan1_kernel,
                              hipFuncAttributeMaxDynamicSharedMemorySize,
                              SCAN1_LDS);

    const size_t state_bytes = (size_t)BATCH * (100 + 50 + 50 + 25 + 25) * sizeof(float);
    int CH = 0;
    for (int c = 128; c >= 8; c >>= 1) {
        size_t need = (size_t)c * BATCH * 700 * sizeof(float) + state_bytes;
        if (need <= ws_size) { CH = c; break; }
    }
    if (CH == 0) return;  // soft-fail: workspace too small

    char* ws = (char*)d_ws;
    float* xg1c    = (float*)ws;                                   // CH*B*400
    float* h1c     = xg1c + (size_t)CH * BATCH * 400;              // CH*B*100
    float* xg2c    = h1c  + (size_t)CH * BATCH * 100;              // CH*B*200
    float* c1state = xg2c + (size_t)CH * BATCH * 200;              // B*100
    float* h2state = c1state + (size_t)BATCH * 100;                // B*50
    float* c2state = h2state + (size_t)BATCH * 50;                 // B*50
    float* h3state = c2state + (size_t)BATCH * 50;                 // B*25
    float* c3state = h3state + (size_t)BATCH * 25;                 // B*25

    const int rowtiles = CH * BATCH / 64;

    for (int t0 = 0; t0 < T_STEPS; t0 += CH) {
        gemm1_kernel<<<rowtiles, 448, 0, stream>>>(
            x + (size_t)t0 * BATCH * 64, w_ih1, b_ih1, b_hh1, xg1c);
        scan1_kernel<<<BATCH / 2, 256, SCAN1_LDS, stream>>>(
            xg1c, w_hh1, h1c, c1state, t0, CH);
        gemm2_kernel<<<rowtiles, 448, 0, stream>>>(h1c, w_ih2, b_ih2, b_hh2, xg2c);
        scan23_kernel<<<BATCH, 384, 0, stream>>>(
            xg2c, w_hh2, w_ih3, w_hh3, b_ih3, b_hh3, w_lin, b_lin, out,
            h2state, c2state, h3state, c3state, t0, CH);
    }
}

// Round 9
// 1950.792 us; speedup vs baseline: 2.9608x; 1.3451x over previous
//
#include <hip/hip_runtime.h>
#include <math.h>

#define T_STEPS 512
#define BATCH   512

__device__ __forceinline__ float sigmoidf_(float x) {
    return 1.0f / (1.0f + __expf(-x));        // x<<0 -> 1/inf = 0, safe
}
__device__ __forceinline__ float tanhf_(float x) {
    float ax = fabsf(x);
    float e  = __expf(-2.0f * ax);            // in (0,1], never overflows
    float t  = (1.0f - e) / (1.0f + e);
    return copysignf(t, x);
}
__device__ __forceinline__ float4 ld4(const float* p) {
    return make_float4(p[0], p[1], p[2], p[3]);
}

#define PINF(f)  asm volatile("" : "+v"(f))
#define PIN4(v)  { PINF(v.x); PINF(v.y); PINF(v.z); PINF(v.w); }
// In-loop anti-remat pin: claims to modify the value EVERY iteration, so the
// allocator cannot re-materialize it from its original global load (rounds
// 3-6: compiler remats weight loads each step; pre-loop pins don't stop it).
#define KEEP4(v) asm volatile("" : "+v"(v.x), "+v"(v.y), "+v"(v.z), "+v"(v.w))

// ---------------------------------------------------------------------------
// gemm1: xg[r][j] = b[j] + sum_k A[r][k]*W[j][k], K=64, N=400. (round-6)
// ---------------------------------------------------------------------------
__global__ __launch_bounds__(448, 2) void gemm1_kernel(
    const float* __restrict__ A, const float* __restrict__ W,
    const float* __restrict__ bih, const float* __restrict__ bhh,
    float* __restrict__ xg)
{
    __shared__ __align__(16) float As[64 * 64];
    const int tid = threadIdx.x;

    float4 W00,W01,W02,W03,W04,W05,W06,W07,W08,W09,W10,W11,W12,W13,W14,W15;
    float bias = 0.0f;
    if (tid < 400) {
        bias = bih[tid] + bhh[tid];
        const float* wp = W + tid * 64;
        W00=ld4(wp+ 0); W01=ld4(wp+ 4); W02=ld4(wp+ 8); W03=ld4(wp+12);
        W04=ld4(wp+16); W05=ld4(wp+20); W06=ld4(wp+24); W07=ld4(wp+28);
        W08=ld4(wp+32); W09=ld4(wp+36); W10=ld4(wp+40); W11=ld4(wp+44);
        W12=ld4(wp+48); W13=ld4(wp+52); W14=ld4(wp+56); W15=ld4(wp+60);
    }

    const size_t r0 = (size_t)blockIdx.x * 64;
    const float4* Ag = (const float4*)(A + r0 * 64);
    float4* As4 = (float4*)As;
    for (int i = tid; i < 64 * 16; i += 448) As4[i] = Ag[i];
    __syncthreads();

    if (tid < 400) {
        for (int r = 0; r < 64; ++r) {
            const float4* a4 = (const float4*)(As + r * 64);
            float a0 = bias, a1 = 0.0f;
#define G1V(WV, I) { float4 v = a4[I]; \
            a0 = fmaf(v.x, WV.x, a0); a1 = fmaf(v.y, WV.y, a1); \
            a0 = fmaf(v.z, WV.z, a0); a1 = fmaf(v.w, WV.w, a1); }
            G1V(W00,0) G1V(W01,1) G1V(W02,2) G1V(W03,3)
            G1V(W04,4) G1V(W05,5) G1V(W06,6) G1V(W07,7)
            G1V(W08,8) G1V(W09,9) G1V(W10,10) G1V(W11,11)
            G1V(W12,12) G1V(W13,13) G1V(W14,14) G1V(W15,15)
#undef G1V
            xg[(r0 + r) * 400 + tid] = a0 + a1;
        }
    }
}

// ---------------------------------------------------------------------------
// gemm2: K=100, N=200, split-K slots. (round-6)
// ---------------------------------------------------------------------------
__global__ __launch_bounds__(448, 2) void gemm2_kernel(
    const float* __restrict__ A, const float* __restrict__ W,
    const float* __restrict__ bih, const float* __restrict__ bhh,
    float* __restrict__ xg)
{
    __shared__ __align__(16) float As[64 * 104];
    __shared__ __align__(16) float ps[8][2][200];

    const int tid  = threadIdx.x;
    const bool slot = (tid < 400);
    const int q = slot ? tid / 200 : 0;
    const int j = slot ? tid % 200 : 0;

    float4 W00,W01,W02,W03,W04,W05,W06,W07,W08,W09,W10,W11,W12;
    float bias = 0.0f;
    if (slot) {
        if (q == 0) bias = bih[j] + bhh[j];
        const float* wp = W + j * 100 + q * 52;
        W00=ld4(wp+ 0); W01=ld4(wp+ 4); W02=ld4(wp+ 8); W03=ld4(wp+12);
        W04=ld4(wp+16); W05=ld4(wp+20); W06=ld4(wp+24); W07=ld4(wp+28);
        W08=ld4(wp+32); W09=ld4(wp+36); W10=ld4(wp+40); W11=ld4(wp+44);
        W12 = q ? make_float4(0.f,0.f,0.f,0.f) : ld4(wp+48);
    }

    const size_t r0 = (size_t)blockIdx.x * 64;
    const float2* A2 = (const float2*)(A + r0 * 100);
    float2* As2 = (float2*)As;
    for (int i = tid; i < 64 * 50; i += 448) {
        int r = i / 50, k2 = i % 50;
        As2[r * 52 + k2] = A2[i];
    }
    if (tid < 64) {
        As[tid*104+100]=0.f; As[tid*104+101]=0.f;
        As[tid*104+102]=0.f; As[tid*104+103]=0.f;
    }
    __syncthreads();

    const float4* As4 = (const float4*)As;
    const int q13 = q * 13;
    const float base = (q == 0) ? bias : 0.0f;
    for (int g = 0; g < 8; ++g) {
        const int rb = g * 8;
        if (slot) {
#define G2V(P, WV, I) { float4 v = P[I]; \
            A0 = fmaf(v.x, WV.x, A0); A1 = fmaf(v.y, WV.y, A1); \
            A0 = fmaf(v.z, WV.z, A0); A1 = fmaf(v.w, WV.w, A1); }
#define G2ROW(RR) { const float4* a4 = As4 + (rb + RR) * 26 + q13; \
            float A0 = base, A1 = 0.0f; \
            G2V(a4,W00,0) G2V(a4,W01,1) G2V(a4,W02,2) G2V(a4,W03,3) \
            G2V(a4,W04,4) G2V(a4,W05,5) G2V(a4,W06,6) G2V(a4,W07,7) \
            G2V(a4,W08,8) G2V(a4,W09,9) G2V(a4,W10,10) G2V(a4,W11,11) \
            G2V(a4,W12,12) \
            ps[RR][q][j] = A0 + A1; }
            G2ROW(0) G2ROW(1) G2ROW(2) G2ROW(3)
            G2ROW(4) G2ROW(5) G2ROW(6) G2ROW(7)
#undef G2ROW
#undef G2V
        }
        __syncthreads();
        if (tid < 200) {
            #pragma unroll
            for (int rr = 0; rr < 8; ++rr)
                xg[(r0 + rb + rr) * 200 + tid] = ps[rr][0][tid] + ps[rr][1][tid];
        }
        __syncthreads();
    }
}

// ---------------------------------------------------------------------------
// scan1: round-5 split-K structure + IN-LOOP anti-remat pins (the single
// change this round). 256 blocks (2 batch rows), 832 threads:
//   tid 0..415   : slots q=0 (j=tid,     w_hh1[j][0:52] in 13 named vecs)
//   tid 416..815 : slots q=1 (j=tid-416, w_hh1[j][52:100] in 12 vecs + zero)
//   tid 0..199   : update threads (bn=tid/100, u=tid%100), c in register
// h in LDS h_s[2][104] (pad=0), partials ps[2][2][400] (stride-1).
// ---------------------------------------------------------------------------
__global__ __launch_bounds__(832, 3) void scan1_kernel(
    const float* __restrict__ xg,     // [CH*B, 400] chunk-local
    const float* __restrict__ w_hh,   // [400, 100]
    float* __restrict__ h1c,          // [CH*B, 100] chunk-local
    float* __restrict__ c1state,      // [B, 100]
    int t0, int CH)
{
    __shared__ __align__(16) float h_s[2][104];
    __shared__ __align__(16) float ps[2][2][400];

    const int tid   = threadIdx.x;
    const int q     = (tid >= 416) ? 1 : 0;
    const int j     = tid - 416 * q;
    const bool slot = (j < 400);
    const int brow0 = blockIdx.x * 2;

    float4 W00,W01,W02,W03,W04,W05,W06,W07,W08,W09,W10,W11,W12;
    if (slot) {
        const float* wp = w_hh + j * 100 + q * 52;
        W00=ld4(wp+ 0); W01=ld4(wp+ 4); W02=ld4(wp+ 8); W03=ld4(wp+12);
        W04=ld4(wp+16); W05=ld4(wp+20); W06=ld4(wp+24); W07=ld4(wp+28);
        W08=ld4(wp+32); W09=ld4(wp+36); W10=ld4(wp+40); W11=ld4(wp+44);
        W12 = q ? make_float4(0.f,0.f,0.f,0.f) : ld4(wp+48);
    }

    float c = 0.0f;
    if (tid < 200) {
        int bn = tid / 100, u = tid % 100;
        if (t0 == 0) {
            h_s[bn][u] = 0.0f;
        } else {
            h_s[bn][u] = h1c[((size_t)(CH - 1) * BATCH + brow0 + bn) * 100 + u];
            c          = c1state[(size_t)(brow0 + bn) * 100 + u];
        }
    }
    if (tid >= 200 && tid < 208) {          // zero the float4 pad [100..103]
        int i = tid - 200;
        h_s[i >> 2][100 + (i & 3)] = 0.0f;
    }

    float xgv0 = 0.0f, xgv1 = 0.0f;
    if (slot && q == 0) {
        xgv0 = xg[(size_t)brow0 * 400 + j];
        xgv1 = xg[((size_t)brow0 + 1) * 400 + j];
    }
    __syncthreads();

    const int hq = q * 13;
    for (int tl = 0; tl < CH; ++tl) {
        float pre0 = 0.0f, pre1 = 0.0f;
        if (slot && q == 0 && tl + 1 < CH) {
            pre0 = xg[((size_t)(tl + 1) * BATCH + brow0) * 400 + j];
            pre1 = xg[((size_t)(tl + 1) * BATCH + brow0 + 1) * 400 + j];
        }
        if (slot) {
            // anti-remat: "modify" weights each iteration so the allocator
            // must carry them in VGPRs instead of re-loading from global.
            KEEP4(W00); KEEP4(W01); KEEP4(W02); KEEP4(W03);
            KEEP4(W04); KEEP4(W05); KEEP4(W06); KEEP4(W07);
            KEEP4(W08); KEEP4(W09); KEEP4(W10); KEEP4(W11);
            KEEP4(W12);
            const float4* h0 = (const float4*)h_s[0] + hq;
            const float4* h1 = (const float4*)h_s[1] + hq;
            float a00 = xgv0, a01 = 0.0f, a10 = xgv1, a11 = 0.0f;
#define S1ACC(WV, I) { float4 v0 = h0[I], v1 = h1[I]; \
            a00 = fmaf(v0.x, WV.x, a00); a10 = fmaf(v1.x, WV.x, a10); \
            a01 = fmaf(v0.y, WV.y, a01); a11 = fmaf(v1.y, WV.y, a11); \
            a00 = fmaf(v0.z, WV.z, a00); a10 = fmaf(v1.z, WV.z, a10); \
            a01 = fmaf(v0.w, WV.w, a01); a11 = fmaf(v1.w, WV.w, a11); }
            S1ACC(W00,0) S1ACC(W01,1) S1ACC(W02,2) S1ACC(W03,3)
            S1ACC(W04,4) S1ACC(W05,5) S1ACC(W06,6) S1ACC(W07,7)
            S1ACC(W08,8) S1ACC(W09,9) S1ACC(W10,10) S1ACC(W11,11)
            S1ACC(W12,12)
#undef S1ACC
            ps[0][q][j] = a00 + a01;
            ps[1][q][j] = a10 + a11;
        }
        __syncthreads();
        xgv0 = pre0; xgv1 = pre1;
        if (tid < 200) {
            int bn = tid / 100, u = tid % 100;
            float gi = ps[bn][0][u]       + ps[bn][1][u];
            float gf = ps[bn][0][100 + u] + ps[bn][1][100 + u];
            float gg = ps[bn][0][200 + u] + ps[bn][1][200 + u];
            float go = ps[bn][0][300 + u] + ps[bn][1][300 + u];
            c = sigmoidf_(gf) * c + sigmoidf_(gi) * tanhf_(gg);
            float h = sigmoidf_(go) * tanhf_(c);
            h_s[bn][u] = h;
            h1c[((size_t)tl * BATCH + brow0 + bn) * 100 + u] = h;
        }
        __syncthreads();
    }
    if (tid < 200) {
        int bn = tid / 100, u = tid % 100;
        c1state[(size_t)(brow0 + bn) * 100 + u] = c;
    }
}

// ---------------------------------------------------------------------------
// scan23: layers 2+3 + linear, pipelined (round-6 version, unchanged).
// ---------------------------------------------------------------------------
__global__ __launch_bounds__(384, 2) void scan23_kernel(
    const float* __restrict__ xg2,    // [CH*B, 200] chunk-local (biases folded)
    const float* __restrict__ w_hh2,  // [200, 50]
    const float* __restrict__ w_ih3,  // [100, 50]
    const float* __restrict__ w_hh3,  // [100, 25]
    const float* __restrict__ b_ih3, const float* __restrict__ b_hh3,
    const float* __restrict__ w_lin, const float* __restrict__ b_lin,
    float* __restrict__ out,          // [T*B]
    float* __restrict__ h2state, float* __restrict__ c2state,  // [B,50]
    float* __restrict__ h3state, float* __restrict__ c3state,  // [B,25]
    int t0, int CH)
{
    __shared__ __align__(16) float h2_s[52];
    __shared__ __align__(16) float x3_s[2][52];
    __shared__ __align__(16) float h3_s[28];
    __shared__ __align__(16) float h3o_s[2][28];
    __shared__ __align__(16) float g2_s[200];
    __shared__ __align__(16) float g3_s[100];

    const int tid  = threadIdx.x;
    const int brow = blockIdx.x;

    float4 WA0,WA1,WA2,WA3,WA4,WA5,WA6,WA7,WA8,WA9,WA10,WA11,WA12;
    float4 WB0,WB1,WB2,WB3,WB4,WB5,WB6;
    float bias = 0.0f;

#define PINA13 { PIN4(WA0) PIN4(WA1) PIN4(WA2) PIN4(WA3) PIN4(WA4) PIN4(WA5) \
                 PIN4(WA6) PIN4(WA7) PIN4(WA8) PIN4(WA9) PIN4(WA10) PIN4(WA11) \
                 PIN4(WA12) }
#define PINB7  { PIN4(WB0) PIN4(WB1) PIN4(WB2) PIN4(WB3) PIN4(WB4) PIN4(WB5) \
                 PIN4(WB6) }

    if (tid < 200) {                       // L2 gates: w_hh2 row (50 + 2 zeros)
        const float* p = w_hh2 + tid * 50;
        WA0=ld4(p+ 0); WA1=ld4(p+ 4); WA2=ld4(p+ 8); WA3=ld4(p+12);
        WA4=ld4(p+16); WA5=ld4(p+20); WA6=ld4(p+24); WA7=ld4(p+28);
        WA8=ld4(p+32); WA9=ld4(p+36); WA10=ld4(p+40); WA11=ld4(p+44);
        WA12 = make_float4(p[48], p[49], 0.f, 0.f);
        PINA13
    } else if (tid >= 256 && tid < 356) {  // L3 gates
        int jj = tid - 256;
        bias = b_ih3[jj] + b_hh3[jj];
        const float* p = w_ih3 + jj * 50;
        WA0=ld4(p+ 0); WA1=ld4(p+ 4); WA2=ld4(p+ 8); WA3=ld4(p+12);
        WA4=ld4(p+16); WA5=ld4(p+20); WA6=ld4(p+24); WA7=ld4(p+28);
        WA8=ld4(p+32); WA9=ld4(p+36); WA10=ld4(p+40); WA11=ld4(p+44);
        WA12 = make_float4(p[48], p[49], 0.f, 0.f);
        const float* p2 = w_hh3 + jj * 25;
        WB0=ld4(p2+ 0); WB1=ld4(p2+ 4); WB2=ld4(p2+ 8);
        WB3=ld4(p2+12); WB4=ld4(p2+16); WB5=ld4(p2+20);
        WB6 = make_float4(p2[24], 0.f, 0.f, 0.f);
        PINA13
        PINB7
        PINF(bias);
    } else if (tid == 370) {               // linear (7 vecs in WA0..WA6)
        bias = b_lin[0];
        WA0=ld4(w_lin+ 0); WA1=ld4(w_lin+ 4); WA2=ld4(w_lin+ 8);
        WA3=ld4(w_lin+12); WA4=ld4(w_lin+16); WA5=ld4(w_lin+20);
        WA6 = make_float4(w_lin[24], 0.f, 0.f, 0.f);
        PIN4(WA0) PIN4(WA1) PIN4(WA2) PIN4(WA3) PIN4(WA4) PIN4(WA5) PIN4(WA6)
        PINF(bias);
    }
#undef PINA13
#undef PINB7

    float c2 = 0.0f, c3 = 0.0f;
    if (tid < 52)  { h2_s[tid] = 0.0f; x3_s[0][tid] = 0.0f; x3_s[1][tid] = 0.0f; }
    if (tid >= 52 && tid < 80)  h3_s[tid - 52] = 0.0f;
    if (tid >= 80 && tid < 108) h3o_s[0][tid - 80] = 0.0f;
    if (tid >= 108 && tid < 136) h3o_s[1][tid - 108] = 0.0f;
    __syncthreads();
    if (t0 > 0) {
        if (tid < 50) {
            h2_s[tid] = h2state[(size_t)brow * 50 + tid];
            c2        = c2state[(size_t)brow * 50 + tid];
        }
        if (tid >= 256 && tid < 281) {
            int u = tid - 256;
            h3_s[u] = h3state[(size_t)brow * 25 + u];
            c3      = c3state[(size_t)brow * 25 + u];
        }
    }
    float xgv = (tid < 200) ? xg2[(size_t)brow * 200 + tid] : 0.0f;
    __syncthreads();

    for (int it = 0; it < CH + 2; ++it) {
        float pre = (tid < 200 && it + 1 < CH)
                  ? xg2[((size_t)(it + 1) * BATCH + brow) * 200 + tid] : 0.0f;

        if (tid < 200 && it < CH) {                 // L2 gates, step t0+it
            const float4* hv = (const float4*)h2_s;
            float a0 = xgv, a1 = 0.0f;
#define SCV(PV, WV, I) { float4 v = PV[I]; \
            a0 = fmaf(v.x, WV.x, a0); a1 = fmaf(v.y, WV.y, a1); \
            a0 = fmaf(v.z, WV.z, a0); a1 = fmaf(v.w, WV.w, a1); }
            SCV(hv,WA0,0) SCV(hv,WA1,1) SCV(hv,WA2,2) SCV(hv,WA3,3)
            SCV(hv,WA4,4) SCV(hv,WA5,5) SCV(hv,WA6,6) SCV(hv,WA7,7)
            SCV(hv,WA8,8) SCV(hv,WA9,9) SCV(hv,WA10,10) SCV(hv,WA11,11)
            SCV(hv,WA12,12)
            g2_s[tid] = a0 + a1;
        }

        if (tid >= 256 && tid < 356 && it >= 1 && it <= CH) {  // L3 gates
            const float4* xv = (const float4*)x3_s[(it - 1) & 1];
            const float4* hv = (const float4*)h3_s;
            float a0 = bias, a1 = 0.0f;
            SCV(xv,WA0,0) SCV(xv,WA1,1) SCV(xv,WA2,2) SCV(xv,WA3,3)
            SCV(xv,WA4,4) SCV(xv,WA5,5) SCV(xv,WA6,6) SCV(xv,WA7,7)
            SCV(xv,WA8,8) SCV(xv,WA9,9) SCV(xv,WA10,10) SCV(xv,WA11,11)
            SCV(xv,WA12,12)
            SCV(hv,WB0,0) SCV(hv,WB1,1) SCV(hv,WB2,2) SCV(hv,WB3,3)
            SCV(hv,WB4,4) SCV(hv,WB5,5) SCV(hv,WB6,6)
            g3_s[tid - 256] = a0 + a1;
        }

        if (tid == 370 && it >= 2) {               // linear
            const float4* hv = (const float4*)h3o_s[(it - 2) & 1];
            float a0 = bias, a1 = 0.0f;
            SCV(hv,WA0,0) SCV(hv,WA1,1) SCV(hv,WA2,2) SCV(hv,WA3,3)
            SCV(hv,WA4,4) SCV(hv,WA5,5) SCV(hv,WA6,6)
            out[(size_t)(t0 + it - 2) * BATCH + brow] = a0 + a1;
        }
#undef SCV
        __syncthreads();

        if (tid < 200) xgv = pre;

        if (tid < 50 && it < CH) {                  // L2 update
            float gi = g2_s[tid],       gf = g2_s[50 + tid];
            float gg = g2_s[100 + tid], go = g2_s[150 + tid];
            c2 = sigmoidf_(gf) * c2 + sigmoidf_(gi) * tanhf_(gg);
            float h = sigmoidf_(go) * tanhf_(c2);
            h2_s[tid] = h;
            x3_s[it & 1][tid] = h;
        }

        if (tid >= 256 && tid < 281 && it >= 1 && it <= CH) {  // L3 update
            int u = tid - 256;
            float gi = g3_s[u],      gf = g3_s[25 + u];
            float gg = g3_s[50 + u], go = g3_s[75 + u];
            c3 = sigmoidf_(gf) * c3 + sigmoidf_(gi) * tanhf_(gg);
            float h = sigmoidf_(go) * tanhf_(c3);
            h3_s[u] = h;
            h3o_s[(it - 1) & 1][u] = h;
        }
        __syncthreads();
    }

    if (tid < 50) {
        h2state[(size_t)brow * 50 + tid] = h2_s[tid];
        c2state[(size_t)brow * 50 + tid] = c2;
    }
    if (tid >= 256 && tid < 281) {
        int u = tid - 256;
        h3state[(size_t)brow * 25 + u] = h3_s[u];
        c3state[(size_t)brow * 25 + u] = c3;
    }
}

extern "C" void kernel_launch(void* const* d_in, const int* in_sizes, int n_in,
                              void* d_out, int out_size, void* d_ws, size_t ws_size,
                              hipStream_t stream)
{
    const float* x     = (const float*)d_in[0];
    const float* w_ih1 = (const float*)d_in[1];
    const float* w_hh1 = (const float*)d_in[2];
    const float* b_ih1 = (const float*)d_in[3];
    const float* b_hh1 = (const float*)d_in[4];
    const float* w_ih2 = (const float*)d_in[5];
    const float* w_hh2 = (const float*)d_in[6];
    const float* b_ih2 = (const float*)d_in[7];
    const float* b_hh2 = (const float*)d_in[8];
    const float* w_ih3 = (const float*)d_in[9];
    const float* w_hh3 = (const float*)d_in[10];
    const float* b_ih3 = (const float*)d_in[11];
    const float* b_hh3 = (const float*)d_in[12];
    const float* w_lin = (const float*)d_in[13];
    const float* b_lin = (const float*)d_in[14];
    float* out = (float*)d_out;

    const size_t state_bytes = (size_t)BATCH * (100 + 50 + 50 + 25 + 25) * sizeof(float);
    int CH = 0;
    for (int c = 128; c >= 8; c >>= 1) {
        size_t need = (size_t)c * BATCH * 700 * sizeof(float) + state_bytes;
        if (need <= ws_size) { CH = c; break; }
    }
    if (CH == 0) return;  // soft-fail: workspace too small

    char* ws = (char*)d_ws;
    float* xg1c    = (float*)ws;                                   // CH*B*400
    float* h1c     = xg1c + (size_t)CH * BATCH * 400;              // CH*B*100
    float* xg2c    = h1c  + (size_t)CH * BATCH * 100;              // CH*B*200
    float* c1state = xg2c + (size_t)CH * BATCH * 200;              // B*100
    float* h2state = c1state + (size_t)BATCH * 100;                // B*50
    float* c2state = h2state + (size_t)BATCH * 50;                 // B*50
    float* h3state = c2state + (size_t)BATCH * 50;                 // B*25
    float* c3state = h3state + (size_t)BATCH * 25;                 // B*25

    const int rowtiles = CH * BATCH / 64;

    for (int t0 = 0; t0 < T_STEPS; t0 += CH) {
        gemm1_kernel<<<rowtiles, 448, 0, stream>>>(
            x + (size_t)t0 * BATCH * 64, w_ih1, b_ih1, b_hh1, xg1c);
        scan1_kernel<<<BATCH / 2, 832, 0, stream>>>(xg1c, w_hh1, h1c, c1state, t0, CH);
        gemm2_kernel<<<rowtiles, 448, 0, stream>>>(h1c, w_ih2, b_ih2, b_hh2, xg2c);
        scan23_kernel<<<BATCH, 384, 0, stream>>>(
            xg2c, w_hh2, w_ih3, w_hh3, b_ih3, b_hh3, w_lin, b_lin, out,
            h2state, c2state, h3state, c3state, t0, CH);
    }
}

// Round 10
// 1931.461 us; speedup vs baseline: 2.9905x; 1.0100x over previous
//
#include <hip/hip_runtime.h>
#include <math.h>

#define T_STEPS 512
#define BATCH   512

__device__ __forceinline__ float sigmoidf_(float x) {
    return 1.0f / (1.0f + __expf(-x));        // x<<0 -> 1/inf = 0, safe
}
__device__ __forceinline__ float tanhf_(float x) {
    float ax = fabsf(x);
    float e  = __expf(-2.0f * ax);            // in (0,1], never overflows
    float t  = (1.0f - e) / (1.0f + e);
    return copysignf(t, x);
}
__device__ __forceinline__ float4 ld4(const float* p) {
    return make_float4(p[0], p[1], p[2], p[3]);
}

// OPAQUE 16B load: the value is produced by a volatile asm -> the register
// allocator can NEITHER rematerialize it from memory per-iteration (rounds
// 3-9 pathology: VGPR=44, weights re-fetched from L2 every step) NOR sink
// it into the loop. Its only choices: keep in VGPRs (budget allows) or
// spill to scratch (would show in WRITE_SIZE -> diagnostic either way).
__device__ __forceinline__ float4 ldg4_opaque(const float* p) {
    float4 v;
    asm volatile("global_load_dwordx4 %0, %1, off\n\t"
                 "s_waitcnt vmcnt(0)"
                 : "=v"(v) : "v"(p) : "memory");
    return v;
}

#define PINF(f)  asm volatile("" : "+v"(f))
#define PIN4(v)  { PINF(v.x); PINF(v.y); PINF(v.z); PINF(v.w); }

// ---------------------------------------------------------------------------
// gemm1: xg[r][j] = b[j] + sum_k A[r][k]*W[j][k], K=64, N=400. (round-6)
// ---------------------------------------------------------------------------
__global__ __launch_bounds__(448, 2) void gemm1_kernel(
    const float* __restrict__ A, const float* __restrict__ W,
    const float* __restrict__ bih, const float* __restrict__ bhh,
    float* __restrict__ xg)
{
    __shared__ __align__(16) float As[64 * 64];
    const int tid = threadIdx.x;

    float4 W00,W01,W02,W03,W04,W05,W06,W07,W08,W09,W10,W11,W12,W13,W14,W15;
    float bias = 0.0f;
    if (tid < 400) {
        bias = bih[tid] + bhh[tid];
        const float* wp = W + tid * 64;
        W00=ld4(wp+ 0); W01=ld4(wp+ 4); W02=ld4(wp+ 8); W03=ld4(wp+12);
        W04=ld4(wp+16); W05=ld4(wp+20); W06=ld4(wp+24); W07=ld4(wp+28);
        W08=ld4(wp+32); W09=ld4(wp+36); W10=ld4(wp+40); W11=ld4(wp+44);
        W12=ld4(wp+48); W13=ld4(wp+52); W14=ld4(wp+56); W15=ld4(wp+60);
    }

    const size_t r0 = (size_t)blockIdx.x * 64;
    const float4* Ag = (const float4*)(A + r0 * 64);
    float4* As4 = (float4*)As;
    for (int i = tid; i < 64 * 16; i += 448) As4[i] = Ag[i];
    __syncthreads();

    if (tid < 400) {
        for (int r = 0; r < 64; ++r) {
            const float4* a4 = (const float4*)(As + r * 64);
            float a0 = bias, a1 = 0.0f;
#define G1V(WV, I) { float4 v = a4[I]; \
            a0 = fmaf(v.x, WV.x, a0); a1 = fmaf(v.y, WV.y, a1); \
            a0 = fmaf(v.z, WV.z, a0); a1 = fmaf(v.w, WV.w, a1); }
            G1V(W00,0) G1V(W01,1) G1V(W02,2) G1V(W03,3)
            G1V(W04,4) G1V(W05,5) G1V(W06,6) G1V(W07,7)
            G1V(W08,8) G1V(W09,9) G1V(W10,10) G1V(W11,11)
            G1V(W12,12) G1V(W13,13) G1V(W14,14) G1V(W15,15)
#undef G1V
            xg[(r0 + r) * 400 + tid] = a0 + a1;
        }
    }
}

// ---------------------------------------------------------------------------
// gemm2: K=100, N=200, split-K slots. (round-6)
// ---------------------------------------------------------------------------
__global__ __launch_bounds__(448, 2) void gemm2_kernel(
    const float* __restrict__ A, const float* __restrict__ W,
    const float* __restrict__ bih, const float* __restrict__ bhh,
    float* __restrict__ xg)
{
    __shared__ __align__(16) float As[64 * 104];
    __shared__ __align__(16) float ps[8][2][200];

    const int tid  = threadIdx.x;
    const bool slot = (tid < 400);
    const int q = slot ? tid / 200 : 0;
    const int j = slot ? tid % 200 : 0;

    float4 W00,W01,W02,W03,W04,W05,W06,W07,W08,W09,W10,W11,W12;
    float bias = 0.0f;
    if (slot) {
        if (q == 0) bias = bih[j] + bhh[j];
        const float* wp = W + j * 100 + q * 52;
        W00=ld4(wp+ 0); W01=ld4(wp+ 4); W02=ld4(wp+ 8); W03=ld4(wp+12);
        W04=ld4(wp+16); W05=ld4(wp+20); W06=ld4(wp+24); W07=ld4(wp+28);
        W08=ld4(wp+32); W09=ld4(wp+36); W10=ld4(wp+40); W11=ld4(wp+44);
        W12 = q ? make_float4(0.f,0.f,0.f,0.f) : ld4(wp+48);
    }

    const size_t r0 = (size_t)blockIdx.x * 64;
    const float2* A2 = (const float2*)(A + r0 * 100);
    float2* As2 = (float2*)As;
    for (int i = tid; i < 64 * 50; i += 448) {
        int r = i / 50, k2 = i % 50;
        As2[r * 52 + k2] = A2[i];
    }
    if (tid < 64) {
        As[tid*104+100]=0.f; As[tid*104+101]=0.f;
        As[tid*104+102]=0.f; As[tid*104+103]=0.f;
    }
    __syncthreads();

    const float4* As4 = (const float4*)As;
    const int q13 = q * 13;
    const float base = (q == 0) ? bias : 0.0f;
    for (int g = 0; g < 8; ++g) {
        const int rb = g * 8;
        if (slot) {
#define G2V(P, WV, I) { float4 v = P[I]; \
            A0 = fmaf(v.x, WV.x, A0); A1 = fmaf(v.y, WV.y, A1); \
            A0 = fmaf(v.z, WV.z, A0); A1 = fmaf(v.w, WV.w, A1); }
#define G2ROW(RR) { const float4* a4 = As4 + (rb + RR) * 26 + q13; \
            float A0 = base, A1 = 0.0f; \
            G2V(a4,W00,0) G2V(a4,W01,1) G2V(a4,W02,2) G2V(a4,W03,3) \
            G2V(a4,W04,4) G2V(a4,W05,5) G2V(a4,W06,6) G2V(a4,W07,7) \
            G2V(a4,W08,8) G2V(a4,W09,9) G2V(a4,W10,10) G2V(a4,W11,11) \
            G2V(a4,W12,12) \
            ps[RR][q][j] = A0 + A1; }
            G2ROW(0) G2ROW(1) G2ROW(2) G2ROW(3)
            G2ROW(4) G2ROW(5) G2ROW(6) G2ROW(7)
#undef G2ROW
#undef G2V
        }
        __syncthreads();
        if (tid < 200) {
            #pragma unroll
            for (int rr = 0; rr < 8; ++rr)
                xg[(r0 + rb + rr) * 200 + tid] = ps[rr][0][tid] + ps[rr][1][tid];
        }
        __syncthreads();
    }
}

// ---------------------------------------------------------------------------
// scan1: round-5/9 split-K structure, weights loaded via OPAQUE asm loads
// (the single change this round; KEEP4/PIN removed). 256 blocks (2 batch
// rows), 832 threads:
//   tid 0..415   : slots q=0 (j=tid,     w_hh1[j][0:52] in 13 opaque vecs)
//   tid 416..815 : slots q=1 (j=tid-416, w_hh1[j][52:100] in 12 vecs + zero)
//   tid 0..199   : update threads (bn=tid/100, u=tid%100), c in register
// h in LDS h_s[2][104] (pad=0), partials ps[2][2][400] (stride-1).
// ---------------------------------------------------------------------------
__global__ __launch_bounds__(832, 3) void scan1_kernel(
    const float* __restrict__ xg,     // [CH*B, 400] chunk-local
    const float* __restrict__ w_hh,   // [400, 100]
    float* __restrict__ h1c,          // [CH*B, 100] chunk-local
    float* __restrict__ c1state,      // [B, 100]
    int t0, int CH)
{
    __shared__ __align__(16) float h_s[2][104];
    __shared__ __align__(16) float ps[2][2][400];

    const int tid   = threadIdx.x;
    const int q     = (tid >= 416) ? 1 : 0;
    const int j     = tid - 416 * q;
    const bool slot = (j < 400);
    const int brow0 = blockIdx.x * 2;

    float4 W00,W01,W02,W03,W04,W05,W06,W07,W08,W09,W10,W11,W12;
    if (slot) {
        const float* wp = w_hh + j * 100 + q * 52;
        W00=ldg4_opaque(wp+ 0); W01=ldg4_opaque(wp+ 4);
        W02=ldg4_opaque(wp+ 8); W03=ldg4_opaque(wp+12);
        W04=ldg4_opaque(wp+16); W05=ldg4_opaque(wp+20);
        W06=ldg4_opaque(wp+24); W07=ldg4_opaque(wp+28);
        W08=ldg4_opaque(wp+32); W09=ldg4_opaque(wp+36);
        W10=ldg4_opaque(wp+40); W11=ldg4_opaque(wp+44);
        W12 = q ? make_float4(0.f,0.f,0.f,0.f) : ldg4_opaque(wp+48);
    }

    float c = 0.0f;
    if (tid < 200) {
        int bn = tid / 100, u = tid % 100;
        if (t0 == 0) {
            h_s[bn][u] = 0.0f;
        } else {
            h_s[bn][u] = h1c[((size_t)(CH - 1) * BATCH + brow0 + bn) * 100 + u];
            c          = c1state[(size_t)(brow0 + bn) * 100 + u];
        }
    }
    if (tid >= 200 && tid < 208) {          // zero the float4 pad [100..103]
        int i = tid - 200;
        h_s[i >> 2][100 + (i & 3)] = 0.0f;
    }

    float xgv0 = 0.0f, xgv1 = 0.0f;
    if (slot && q == 0) {
        xgv0 = xg[(size_t)brow0 * 400 + j];
        xgv1 = xg[((size_t)brow0 + 1) * 400 + j];
    }
    __syncthreads();

    const int hq = q * 13;
    for (int tl = 0; tl < CH; ++tl) {
        float pre0 = 0.0f, pre1 = 0.0f;
        if (slot && q == 0 && tl + 1 < CH) {
            pre0 = xg[((size_t)(tl + 1) * BATCH + brow0) * 400 + j];
            pre1 = xg[((size_t)(tl + 1) * BATCH + brow0 + 1) * 400 + j];
        }
        if (slot) {
            const float4* h0 = (const float4*)h_s[0] + hq;
            const float4* h1 = (const float4*)h_s[1] + hq;
            float a00 = xgv0, a01 = 0.0f, a10 = xgv1, a11 = 0.0f;
#define S1ACC(WV, I) { float4 v0 = h0[I], v1 = h1[I]; \
            a00 = fmaf(v0.x, WV.x, a00); a10 = fmaf(v1.x, WV.x, a10); \
            a01 = fmaf(v0.y, WV.y, a01); a11 = fmaf(v1.y, WV.y, a11); \
            a00 = fmaf(v0.z, WV.z, a00); a10 = fmaf(v1.z, WV.z, a10); \
            a01 = fmaf(v0.w, WV.w, a01); a11 = fmaf(v1.w, WV.w, a11); }
            S1ACC(W00,0) S1ACC(W01,1) S1ACC(W02,2) S1ACC(W03,3)
            S1ACC(W04,4) S1ACC(W05,5) S1ACC(W06,6) S1ACC(W07,7)
            S1ACC(W08,8) S1ACC(W09,9) S1ACC(W10,10) S1ACC(W11,11)
            S1ACC(W12,12)
#undef S1ACC
            ps[0][q][j] = a00 + a01;
            ps[1][q][j] = a10 + a11;
        }
        __syncthreads();
        xgv0 = pre0; xgv1 = pre1;
        if (tid < 200) {
            int bn = tid / 100, u = tid % 100;
            float gi = ps[bn][0][u]       + ps[bn][1][u];
            float gf = ps[bn][0][100 + u] + ps[bn][1][100 + u];
            float gg = ps[bn][0][200 + u] + ps[bn][1][200 + u];
            float go = ps[bn][0][300 + u] + ps[bn][1][300 + u];
            c = sigmoidf_(gf) * c + sigmoidf_(gi) * tanhf_(gg);
            float h = sigmoidf_(go) * tanhf_(c);
            h_s[bn][u] = h;
            h1c[((size_t)tl * BATCH + brow0 + bn) * 100 + u] = h;
        }
        __syncthreads();
    }
    if (tid < 200) {
        int bn = tid / 100, u = tid % 100;
        c1state[(size_t)(brow0 + bn) * 100 + u] = c;
    }
}

// ---------------------------------------------------------------------------
// scan23: layers 2+3 + linear, pipelined (round-6 version, unchanged).
// ---------------------------------------------------------------------------
__global__ __launch_bounds__(384, 2) void scan23_kernel(
    const float* __restrict__ xg2,    // [CH*B, 200] chunk-local (biases folded)
    const float* __restrict__ w_hh2,  // [200, 50]
    const float* __restrict__ w_ih3,  // [100, 50]
    const float* __restrict__ w_hh3,  // [100, 25]
    const float* __restrict__ b_ih3, const float* __restrict__ b_hh3,
    const float* __restrict__ w_lin, const float* __restrict__ b_lin,
    float* __restrict__ out,          // [T*B]
    float* __restrict__ h2state, float* __restrict__ c2state,  // [B,50]
    float* __restrict__ h3state, float* __restrict__ c3state,  // [B,25]
    int t0, int CH)
{
    __shared__ __align__(16) float h2_s[52];
    __shared__ __align__(16) float x3_s[2][52];
    __shared__ __align__(16) float h3_s[28];
    __shared__ __align__(16) float h3o_s[2][28];
    __shared__ __align__(16) float g2_s[200];
    __shared__ __align__(16) float g3_s[100];

    const int tid  = threadIdx.x;
    const int brow = blockIdx.x;

    float4 WA0,WA1,WA2,WA3,WA4,WA5,WA6,WA7,WA8,WA9,WA10,WA11,WA12;
    float4 WB0,WB1,WB2,WB3,WB4,WB5,WB6;
    float bias = 0.0f;

#define PINA13 { PIN4(WA0) PIN4(WA1) PIN4(WA2) PIN4(WA3) PIN4(WA4) PIN4(WA5) \
                 PIN4(WA6) PIN4(WA7) PIN4(WA8) PIN4(WA9) PIN4(WA10) PIN4(WA11) \
                 PIN4(WA12) }
#define PINB7  { PIN4(WB0) PIN4(WB1) PIN4(WB2) PIN4(WB3) PIN4(WB4) PIN4(WB5) \
                 PIN4(WB6) }

    if (tid < 200) {                       // L2 gates: w_hh2 row (50 + 2 zeros)
        const float* p = w_hh2 + tid * 50;
        WA0=ld4(p+ 0); WA1=ld4(p+ 4); WA2=ld4(p+ 8); WA3=ld4(p+12);
        WA4=ld4(p+16); WA5=ld4(p+20); WA6=ld4(p+24); WA7=ld4(p+28);
        WA8=ld4(p+32); WA9=ld4(p+36); WA10=ld4(p+40); WA11=ld4(p+44);
        WA12 = make_float4(p[48], p[49], 0.f, 0.f);
        PINA13
    } else if (tid >= 256 && tid < 356) {  // L3 gates
        int jj = tid - 256;
        bias = b_ih3[jj] + b_hh3[jj];
        const float* p = w_ih3 + jj * 50;
        WA0=ld4(p+ 0); WA1=ld4(p+ 4); WA2=ld4(p+ 8); WA3=ld4(p+12);
        WA4=ld4(p+16); WA5=ld4(p+20); WA6=ld4(p+24); WA7=ld4(p+28);
        WA8=ld4(p+32); WA9=ld4(p+36); WA10=ld4(p+40); WA11=ld4(p+44);
        WA12 = make_float4(p[48], p[49], 0.f, 0.f);
        const float* p2 = w_hh3 + jj * 25;
        WB0=ld4(p2+ 0); WB1=ld4(p2+ 4); WB2=ld4(p2+ 8);
        WB3=ld4(p2+12); WB4=ld4(p2+16); WB5=ld4(p2+20);
        WB6 = make_float4(p2[24], 0.f, 0.f, 0.f);
        PINA13
        PINB7
        PINF(bias);
    } else if (tid == 370) {               // linear (7 vecs in WA0..WA6)
        bias = b_lin[0];
        WA0=ld4(w_lin+ 0); WA1=ld4(w_lin+ 4); WA2=ld4(w_lin+ 8);
        WA3=ld4(w_lin+12); WA4=ld4(w_lin+16); WA5=ld4(w_lin+20);
        WA6 = make_float4(w_lin[24], 0.f, 0.f, 0.f);
        PIN4(WA0) PIN4(WA1) PIN4(WA2) PIN4(WA3) PIN4(WA4) PIN4(WA5) PIN4(WA6)
        PINF(bias);
    }
#undef PINA13
#undef PINB7

    float c2 = 0.0f, c3 = 0.0f;
    if (tid < 52)  { h2_s[tid] = 0.0f; x3_s[0][tid] = 0.0f; x3_s[1][tid] = 0.0f; }
    if (tid >= 52 && tid < 80)  h3_s[tid - 52] = 0.0f;
    if (tid >= 80 && tid < 108) h3o_s[0][tid - 80] = 0.0f;
    if (tid >= 108 && tid < 136) h3o_s[1][tid - 108] = 0.0f;
    __syncthreads();
    if (t0 > 0) {
        if (tid < 50) {
            h2_s[tid] = h2state[(size_t)brow * 50 + tid];
            c2        = c2state[(size_t)brow * 50 + tid];
        }
        if (tid >= 256 && tid < 281) {
            int u = tid - 256;
            h3_s[u] = h3state[(size_t)brow * 25 + u];
            c3      = c3state[(size_t)brow * 25 + u];
        }
    }
    float xgv = (tid < 200) ? xg2[(size_t)brow * 200 + tid] : 0.0f;
    __syncthreads();

    for (int it = 0; it < CH + 2; ++it) {
        float pre = (tid < 200 && it + 1 < CH)
                  ? xg2[((size_t)(it + 1) * BATCH + brow) * 200 + tid] : 0.0f;

        if (tid < 200 && it < CH) {                 // L2 gates, step t0+it
            const float4* hv = (const float4*)h2_s;
            float a0 = xgv, a1 = 0.0f;
#define SCV(PV, WV, I) { float4 v = PV[I]; \
            a0 = fmaf(v.x, WV.x, a0); a1 = fmaf(v.y, WV.y, a1); \
            a0 = fmaf(v.z, WV.z, a0); a1 = fmaf(v.w, WV.w, a1); }
            SCV(hv,WA0,0) SCV(hv,WA1,1) SCV(hv,WA2,2) SCV(hv,WA3,3)
            SCV(hv,WA4,4) SCV(hv,WA5,5) SCV(hv,WA6,6) SCV(hv,WA7,7)
            SCV(hv,WA8,8) SCV(hv,WA9,9) SCV(hv,WA10,10) SCV(hv,WA11,11)
            SCV(hv,WA12,12)
            g2_s[tid] = a0 + a1;
        }

        if (tid >= 256 && tid < 356 && it >= 1 && it <= CH) {  // L3 gates
            const float4* xv = (const float4*)x3_s[(it - 1) & 1];
            const float4* hv = (const float4*)h3_s;
            float a0 = bias, a1 = 0.0f;
            SCV(xv,WA0,0) SCV(xv,WA1,1) SCV(xv,WA2,2) SCV(xv,WA3,3)
            SCV(xv,WA4,4) SCV(xv,WA5,5) SCV(xv,WA6,6) SCV(xv,WA7,7)
            SCV(xv,WA8,8) SCV(xv,WA9,9) SCV(xv,WA10,10) SCV(xv,WA11,11)
            SCV(xv,WA12,12)
            SCV(hv,WB0,0) SCV(hv,WB1,1) SCV(hv,WB2,2) SCV(hv,WB3,3)
            SCV(hv,WB4,4) SCV(hv,WB5,5) SCV(hv,WB6,6)
            g3_s[tid - 256] = a0 + a1;
        }

        if (tid == 370 && it >= 2) {               // linear
            const float4* hv = (const float4*)h3o_s[(it - 2) & 1];
            float a0 = bias, a1 = 0.0f;
            SCV(hv,WA0,0) SCV(hv,WA1,1) SCV(hv,WA2,2) SCV(hv,WA3,3)
            SCV(hv,WA4,4) SCV(hv,WA5,5) SCV(hv,WA6,6)
            out[(size_t)(t0 + it - 2) * BATCH + brow] = a0 + a1;
        }
#undef SCV
        __syncthreads();

        if (tid < 200) xgv = pre;

        if (tid < 50 && it < CH) {                  // L2 update
            float gi = g2_s[tid],       gf = g2_s[50 + tid];
            float gg = g2_s[100 + tid], go = g2_s[150 + tid];
            c2 = sigmoidf_(gf) * c2 + sigmoidf_(gi) * tanhf_(gg);
            float h = sigmoidf_(go) * tanhf_(c2);
            h2_s[tid] = h;
            x3_s[it & 1][tid] = h;
        }

        if (tid >= 256 && tid < 281 && it >= 1 && it <= CH) {  // L3 update
            int u = tid - 256;
            float gi = g3_s[u],      gf = g3_s[25 + u];
            float gg = g3_s[50 + u], go = g3_s[75 + u];
            c3 = sigmoidf_(gf) * c3 + sigmoidf_(gi) * tanhf_(gg);
            float h = sigmoidf_(go) * tanhf_(c3);
            h3_s[u] = h;
            h3o_s[(it - 1) & 1][u] = h;
        }
        __syncthreads();
    }

    if (tid < 50) {
        h2state[(size_t)brow * 50 + tid] = h2_s[tid];
        c2state[(size_t)brow * 50 + tid] = c2;
    }
    if (tid >= 256 && tid < 281) {
        int u = tid - 256;
        h3state[(size_t)brow * 25 + u] = h3_s[u];
        c3state[(size_t)brow * 25 + u] = c3;
    }
}

extern "C" void kernel_launch(void* const* d_in, const int* in_sizes, int n_in,
                              void* d_out, int out_size, void* d_ws, size_t ws_size,
                              hipStream_t stream)
{
    const float* x     = (const float*)d_in[0];
    const float* w_ih1 = (const float*)d_in[1];
    const float* w_hh1 = (const float*)d_in[2];
    const float* b_ih1 = (const float*)d_in[3];
    const float* b_hh1 = (const float*)d_in[4];
    const float* w_ih2 = (const float*)d_in[5];
    const float* w_hh2 = (const float*)d_in[6];
    const float* b_ih2 = (const float*)d_in[7];
    const float* b_hh2 = (const float*)d_in[8];
    const float* w_ih3 = (const float*)d_in[9];
    const float* w_hh3 = (const float*)d_in[10];
    const float* b_ih3 = (const float*)d_in[11];
    const float* b_hh3 = (const float*)d_in[12];
    const float* w_lin = (const float*)d_in[13];
    const float* b_lin = (const float*)d_in[14];
    float* out = (float*)d_out;

    const size_t state_bytes = (size_t)BATCH * (100 + 50 + 50 + 25 + 25) * sizeof(float);
    int CH = 0;
    for (int c = 128; c >= 8; c >>= 1) {
        size_t need = (size_t)c * BATCH * 700 * sizeof(float) + state_bytes;
        if (need <= ws_size) { CH = c; break; }
    }
    if (CH == 0) return;  // soft-fail: workspace too small

    char* ws = (char*)d_ws;
    float* xg1c    = (float*)ws;                                   // CH*B*400
    float* h1c     = xg1c + (size_t)CH * BATCH * 400;              // CH*B*100
    float* xg2c    = h1c  + (size_t)CH * BATCH * 100;              // CH*B*200
    float* c1state = xg2c + (size_t)CH * BATCH * 200;              // B*100
    float* h2state = c1state + (size_t)BATCH * 100;                // B*50
    float* c2state = h2state + (size_t)BATCH * 50;                 // B*50
    float* h3state = c2state + (size_t)BATCH * 50;                 // B*25
    float* c3state = h3state + (size_t)BATCH * 25;                 // B*25

    const int rowtiles = CH * BATCH / 64;

    for (int t0 = 0; t0 < T_STEPS; t0 += CH) {
        gemm1_kernel<<<rowtiles, 448, 0, stream>>>(
            x + (size_t)t0 * BATCH * 64, w_ih1, b_ih1, b_hh1, xg1c);
        scan1_kernel<<<BATCH / 2, 832, 0, stream>>>(xg1c, w_hh1, h1c, c1state, t0, CH);
        gemm2_kernel<<<rowtiles, 448, 0, stream>>>(h1c, w_ih2, b_ih2, b_hh2, xg2c);
        scan23_kernel<<<BATCH, 384, 0, stream>>>(
            xg2c, w_hh2, w_ih3, w_hh3, b_ih3, b_hh3, w_lin, b_lin, out,
            h2state, c2state, h3state, c3state, t0, CH);
    }
}